// Round 1
// baseline (580.307 us; speedup 1.0000x reference)
//
#include <hip/hip_runtime.h>

#define NN 50000
#define NE 800000
#define INF 128
#define HID 256     // HEADS*OUT_FEAT
#define NH 4
#define NCLS 40

// ---------------- CSR build ----------------
__global__ void k_count(const int* __restrict__ dst, int* __restrict__ counts) {
    int e = blockIdx.x * 256 + threadIdx.x;
    if (e < NE) atomicAdd(&counts[dst[e]], 1);
}

__global__ void k_scan(const int* __restrict__ counts, int* __restrict__ indptr) {
    __shared__ int part[1024];
    int t = threadIdx.x;
    const int n = NN;
    const int chunk = (n + 1023) / 1024;
    int b = t * chunk;
    int e = b + chunk; if (e > n) e = n;
    int s = 0;
    for (int i = b; i < e; ++i) s += counts[i];
    part[t] = s;
    __syncthreads();
    for (int off = 1; off < 1024; off <<= 1) {
        int v = (t >= off) ? part[t - off] : 0;
        __syncthreads();
        part[t] += v;
        __syncthreads();
    }
    int run = (t > 0) ? part[t - 1] : 0;
    for (int i = b; i < e; ++i) { indptr[i] = run; run += counts[i]; }
    if (t == 1023) indptr[n] = part[1023];
}

__global__ void k_scatter(const int* __restrict__ src, const int* __restrict__ dst,
                          const int* __restrict__ indptr, int* __restrict__ fill,
                          int* __restrict__ srcs) {
    int e = blockIdx.x * 256 + threadIdx.x;
    if (e < NE) {
        int d = dst[e];
        int pos = atomicAdd(&fill[d], 1);
        srcs[indptr[d] + pos] = src[e];
    }
}

// ---------------- layer 1 ----------------
// h1[N,256] = x[N,128] @ W1[128,256]; 8 rows per block, col = tid
__global__ void k_gemm1(const float* __restrict__ x, const float* __restrict__ W,
                        float* __restrict__ h1) {
    __shared__ float xs[8 * 128];
    int t = threadIdx.x;
    int n0 = blockIdx.x * 8;
    ((float4*)xs)[t] = ((const float4*)(x + (size_t)n0 * 128))[t];
    __syncthreads();
    float acc[8] = {0, 0, 0, 0, 0, 0, 0, 0};
    for (int k = 0; k < 128; k += 4) {
        float w0 = W[(k + 0) * 256 + t];
        float w1 = W[(k + 1) * 256 + t];
        float w2 = W[(k + 2) * 256 + t];
        float w3 = W[(k + 3) * 256 + t];
#pragma unroll
        for (int r = 0; r < 8; ++r) {
            float4 xv = *(const float4*)&xs[r * 128 + k];
            acc[r] = fmaf(xv.x, w0, acc[r]);
            acc[r] = fmaf(xv.y, w1, acc[r]);
            acc[r] = fmaf(xv.z, w2, acc[r]);
            acc[r] = fmaf(xv.w, w3, acc[r]);
        }
    }
#pragma unroll
    for (int r = 0; r < 8; ++r) h1[(size_t)(n0 + r) * 256 + t] = acc[r];
}

// el/er[N,4]: one block per node, wave (=64 lanes) per head
__global__ void k_elr1(const float* __restrict__ h1, const float* __restrict__ al,
                       const float* __restrict__ ar, float* __restrict__ el,
                       float* __restrict__ er) {
    int nd = blockIdx.x;
    int t = threadIdx.x;
    float v = h1[(size_t)nd * 256 + t];
    float a = v * al[t];
    float b = v * ar[t];
#pragma unroll
    for (int off = 32; off > 0; off >>= 1) {
        a += __shfl_xor(a, off);
        b += __shfl_xor(b, off);
    }
    if ((t & 63) == 0) {
        int head = t >> 6;
        el[nd * 4 + head] = a;
        er[nd * 4 + head] = b;
    }
}

// aggregation + bias + ELU: one block (256 thr) per destination node
__global__ void k_agg1(const float* __restrict__ h1, const float* __restrict__ el,
                       const float* __restrict__ er, const float* __restrict__ b1,
                       const int* __restrict__ indptr, const int* __restrict__ srcs,
                       float* __restrict__ out) {
    int d = blockIdx.x;
    int t = threadIdx.x;
    int head = t >> 6;
    float er_d = er[d * 4 + head];
    int beg = indptr[d], end = indptr[d + 1];
    float acc = 0.f, den = 0.f;
    for (int j = beg; j < end; ++j) {
        int s = srcs[j];
        float e = el[s * 4 + head] + er_d;
        e = e > 0.f ? e : 0.2f * e;
        float w = __expf(e);
        den += w;
        acc += w * h1[(size_t)s * 256 + t];
    }
    float o = (den > 0.f ? acc / den : 0.f) + b1[t];
    o = o > 0.f ? o : (__expf(o) - 1.f);   // ELU fused (inter-layer activation)
    out[(size_t)d * 256 + t] = o;
}

// ---------------- layer 2 ----------------
// h2[N,40] = elu1[N,256] @ W2[256,40]; 32 rows/block, padded LDS
__global__ void k_gemm2(const float* __restrict__ xin, const float* __restrict__ W,
                        float* __restrict__ h2) {
    __shared__ float xs[32 * 257];
    int t = threadIdx.x;
    int n0 = blockIdx.x * 32;
    for (int i = 0; i < 8; ++i) {
        int f = i * 256 + t;        // float4 slot 0..2047
        int row = f >> 6;           // 0..31
        int col = (f & 63) * 4;
        float4 v;
        if (n0 + row < NN) v = ((const float4*)xin)[(size_t)n0 * 64 + f];
        else v = make_float4(0.f, 0.f, 0.f, 0.f);
        xs[row * 257 + col + 0] = v.x;
        xs[row * 257 + col + 1] = v.y;
        xs[row * 257 + col + 2] = v.z;
        xs[row * 257 + col + 3] = v.w;
    }
    __syncthreads();
    int nl = t & 31;
    int cg = t >> 5;
    int c0 = cg * 5;
    float acc[5] = {0, 0, 0, 0, 0};
    for (int k = 0; k < 256; ++k) {
        float xv = xs[nl * 257 + k];
#pragma unroll
        for (int i = 0; i < 5; ++i) acc[i] = fmaf(xv, W[k * 40 + c0 + i], acc[i]);
    }
    int node = n0 + nl;
    if (node < NN) {
#pragma unroll
        for (int i = 0; i < 5; ++i) h2[(size_t)node * 40 + c0 + i] = acc[i];
    }
}

__global__ void k_elr2(const float* __restrict__ h2, const float* __restrict__ al,
                       const float* __restrict__ ar, float* __restrict__ el,
                       float* __restrict__ er) {
    int nd = blockIdx.x * 256 + threadIdx.x;
    if (nd < NN) {
        float a = 0.f, b = 0.f;
        for (int c = 0; c < NCLS; ++c) {
            float v = h2[(size_t)nd * NCLS + c];
            a += v * al[c];
            b += v * ar[c];
        }
        el[nd] = a;
        er[nd] = b;
    }
}

// final aggregation: 6 nodes per block (40 cols each)
__global__ void k_agg2(const float* __restrict__ h2, const float* __restrict__ el,
                       const float* __restrict__ er, const float* __restrict__ b2,
                       const int* __restrict__ indptr, const int* __restrict__ srcs,
                       float* __restrict__ out) {
    int t = threadIdx.x;
    if (t >= 240) return;
    int g = t / 40;
    int c = t % 40;
    int d = blockIdx.x * 6 + g;
    if (d >= NN) return;
    float er_d = er[d];
    int beg = indptr[d], end = indptr[d + 1];
    float acc = 0.f, den = 0.f;
    for (int j = beg; j < end; ++j) {
        int s = srcs[j];
        float e = el[s] + er_d;
        e = e > 0.f ? e : 0.2f * e;
        float w = __expf(e);
        den += w;
        acc += w * h2[(size_t)s * NCLS + c];
    }
    out[(size_t)d * NCLS + c] = (den > 0.f ? acc / den : 0.f) + b2[c];
}

extern "C" void kernel_launch(void* const* d_in, const int* in_sizes, int n_in,
                              void* d_out, int out_size, void* d_ws, size_t ws_size,
                              hipStream_t stream) {
    const float* x   = (const float*)d_in[0];
    const int*   src = (const int*)d_in[1];
    const int*   dst = (const int*)d_in[2];
    const float* W1  = (const float*)d_in[3];
    const float* al1 = (const float*)d_in[4];
    const float* ar1 = (const float*)d_in[5];
    const float* b1  = (const float*)d_in[6];
    const float* W2  = (const float*)d_in[7];
    const float* al2 = (const float*)d_in[8];
    const float* ar2 = (const float*)d_in[9];
    const float* b2  = (const float*)d_in[10];
    float* out = (float*)d_out;

    float* ws   = (float*)d_ws;
    float* h1   = ws;                                  // N*256
    float* el1  = h1 + (size_t)NN * HID;               // N*4
    float* er1  = el1 + (size_t)NN * NH;               // N*4
    float* elu1 = er1 + (size_t)NN * NH;               // N*256
    float* h2   = elu1 + (size_t)NN * HID;             // N*40
    float* el2  = h2 + (size_t)NN * NCLS;              // N
    float* er2  = el2 + NN;                            // N
    int* counts = (int*)(er2 + NN);                    // N
    int* indptr = counts + NN;                         // N+1
    int* fill   = indptr + NN + 1;                     // N
    int* srcs   = fill + NN;                           // E

    hipMemsetAsync(counts, 0, NN * sizeof(int), stream);
    hipMemsetAsync(fill, 0, NN * sizeof(int), stream);

    k_count<<<(NE + 255) / 256, 256, 0, stream>>>(dst, counts);
    k_scan<<<1, 1024, 0, stream>>>(counts, indptr);
    k_scatter<<<(NE + 255) / 256, 256, 0, stream>>>(src, dst, indptr, fill, srcs);

    k_gemm1<<<NN / 8, 256, 0, stream>>>(x, W1, h1);
    k_elr1<<<NN, 256, 0, stream>>>(h1, al1, ar1, el1, er1);
    k_agg1<<<NN, 256, 0, stream>>>(h1, el1, er1, b1, indptr, srcs, elu1);

    k_gemm2<<<(NN + 31) / 32, 256, 0, stream>>>(elu1, W2, h2);
    k_elr2<<<(NN + 255) / 256, 256, 0, stream>>>(h2, al2, ar2, el2, er2);
    k_agg2<<<(NN + 5) / 6, 256, 0, stream>>>(h2, el2, er2, b2, indptr, srcs, out);
}

// Round 2
// 501.711 us; speedup vs baseline: 1.1567x; 1.1567x over previous
//
#include <hip/hip_runtime.h>

#define NN 50000
#define NE 800000
#define HID 256
#define NCLS 40

// ---------------- CSR build ----------------
__global__ void k_count(const int* __restrict__ dst, int* __restrict__ counts) {
    int e = blockIdx.x * 256 + threadIdx.x;
    if (e < NE) atomicAdd(&counts[dst[e]], 1);
}

__global__ void k_scan(const int* __restrict__ counts, int* __restrict__ indptr) {
    __shared__ int part[1024];
    int t = threadIdx.x;
    const int n = NN;
    const int chunk = (n + 1023) / 1024;
    int b = t * chunk;
    int e = b + chunk; if (e > n) e = n;
    int s = 0;
    for (int i = b; i < e; ++i) s += counts[i];
    part[t] = s;
    __syncthreads();
    for (int off = 1; off < 1024; off <<= 1) {
        int v = (t >= off) ? part[t - off] : 0;
        __syncthreads();
        part[t] += v;
        __syncthreads();
    }
    int run = (t > 0) ? part[t - 1] : 0;
    for (int i = b; i < e; ++i) { indptr[i] = run; run += counts[i]; }
    if (t == 1023) indptr[n] = part[1023];
}

__global__ void k_scatter(const int* __restrict__ src, const int* __restrict__ dst,
                          const int* __restrict__ indptr, int* __restrict__ fill,
                          int* __restrict__ srcs, int* __restrict__ slot) {
    int e = blockIdx.x * 256 + threadIdx.x;
    if (e < NE) {
        int d = dst[e];
        int pos = atomicAdd(&fill[d], 1);
        int j = indptr[d] + pos;
        srcs[j] = src[e];
        slot[e] = j;
    }
}

// ---------------- layer 1 ----------------
// w_el[k,h] = sum_dd W1[k, h*64+dd] * al1[h,dd]; same for w_er
__global__ void k_prew(const float* __restrict__ W1, const float* __restrict__ al,
                       const float* __restrict__ ar, float* __restrict__ wel,
                       float* __restrict__ wer) {
    int t = threadIdx.x;           // 512 threads
    int k = t >> 2, h = t & 3;
    float a = 0.f, b = 0.f;
    for (int dd = 0; dd < 64; ++dd) {
        float w = W1[k * 256 + h * 64 + dd];
        a = fmaf(w, al[h * 64 + dd], a);
        b = fmaf(w, ar[h * 64 + dd], b);
    }
    wel[k * 4 + h] = a;
    wer[k * 4 + h] = b;
}

// el1/er1[N,4] = x @ wel / x @ wer ; 64 nodes per block
__global__ void k_elr1x(const float* __restrict__ x, const float* __restrict__ wel,
                        const float* __restrict__ wer, float* __restrict__ el1,
                        float* __restrict__ er1) {
    __shared__ float xs[64 * 129];
    __shared__ float wels[512], wers[512];
    int t = threadIdx.x;
    int n0 = blockIdx.x * 64;
    wels[t] = wel[t]; wels[256 + t] = wel[256 + t];
    wers[t] = wer[t]; wers[256 + t] = wer[256 + t];
    for (int i = 0; i < 8; ++i) {
        int f = i * 256 + t;         // float4 slot, 2048 total
        int row = f >> 5;
        int col4 = (f & 31) * 4;
        float4 v = make_float4(0.f, 0.f, 0.f, 0.f);
        if (n0 + row < NN) v = ((const float4*)x)[(size_t)n0 * 32 + f];
        xs[row * 129 + col4 + 0] = v.x;
        xs[row * 129 + col4 + 1] = v.y;
        xs[row * 129 + col4 + 2] = v.z;
        xs[row * 129 + col4 + 3] = v.w;
    }
    __syncthreads();
    int node = t & 63;
    int h = t >> 6;                  // uniform per wave
    float a = 0.f, b = 0.f;
    for (int k = 0; k < 128; ++k) {
        float xv = xs[node * 129 + k];
        a = fmaf(xv, wels[k * 4 + h], a);
        b = fmaf(xv, wers[k * 4 + h], b);
    }
    if (n0 + node < NN) {
        el1[(size_t)(n0 + node) * 4 + h] = a;
        er1[(size_t)(n0 + node) * 4 + h] = b;
    }
}

// per-edge softmax weights into CSR slot order
__global__ void k_w1(const int* __restrict__ src, const int* __restrict__ dst,
                     const int* __restrict__ slot, const float* __restrict__ el1,
                     const float* __restrict__ er1, float4* __restrict__ w4) {
    int e = blockIdx.x * 256 + threadIdx.x;
    if (e >= NE) return;
    int s = src[e], d = dst[e], j = slot[e];
    float4 ls = *(const float4*)&el1[(size_t)s * 4];
    float4 rd = *(const float4*)&er1[(size_t)d * 4];
    float e0 = ls.x + rd.x, e1 = ls.y + rd.y, e2 = ls.z + rd.z, e3 = ls.w + rd.w;
    e0 = e0 > 0.f ? e0 : 0.2f * e0;
    e1 = e1 > 0.f ? e1 : 0.2f * e1;
    e2 = e2 > 0.f ? e2 : 0.2f * e2;
    e3 = e3 > 0.f ? e3 : 0.2f * e3;
    w4[j] = make_float4(__expf(e0), __expf(e1), __expf(e2), __expf(e3));
}

// fused: per-dst weighted x-gather (4 heads) -> normalized xagg in LDS -> @W1 + bias + ELU
#define RPB 16
__global__ void k_fused1(const float* __restrict__ x, const float* __restrict__ W1,
                         const float* __restrict__ b1, const int* __restrict__ indptr,
                         const int* __restrict__ srcs, const float4* __restrict__ w4,
                         float* __restrict__ elu1) {
    __shared__ float xs[RPB * 512];
    int t = threadIdx.x;
    int wv = t >> 6, l = t & 63;
    int n0 = blockIdx.x * RPB;
    for (int rr = 0; rr < RPB / 4; ++rr) {
        int r = rr * 4 + wv;
        int d = n0 + r;
        float2 a0 = {0.f, 0.f}, a1 = {0.f, 0.f}, a2 = {0.f, 0.f}, a3 = {0.f, 0.f};
        float d0 = 0.f, d1 = 0.f, d2 = 0.f, d3 = 0.f;
        int beg = indptr[d], end = indptr[d + 1];
        int j = beg;
        for (; j + 1 < end; j += 2) {
            int s0 = srcs[j], s1 = srcs[j + 1];
            float4 wA = w4[j], wB = w4[j + 1];
            float2 xA = *(const float2*)&x[(size_t)s0 * 128 + 2 * l];
            float2 xB = *(const float2*)&x[(size_t)s1 * 128 + 2 * l];
            a0.x = fmaf(wA.x, xA.x, a0.x); a0.y = fmaf(wA.x, xA.y, a0.y);
            a1.x = fmaf(wA.y, xA.x, a1.x); a1.y = fmaf(wA.y, xA.y, a1.y);
            a2.x = fmaf(wA.z, xA.x, a2.x); a2.y = fmaf(wA.z, xA.y, a2.y);
            a3.x = fmaf(wA.w, xA.x, a3.x); a3.y = fmaf(wA.w, xA.y, a3.y);
            d0 += wA.x; d1 += wA.y; d2 += wA.z; d3 += wA.w;
            a0.x = fmaf(wB.x, xB.x, a0.x); a0.y = fmaf(wB.x, xB.y, a0.y);
            a1.x = fmaf(wB.y, xB.x, a1.x); a1.y = fmaf(wB.y, xB.y, a1.y);
            a2.x = fmaf(wB.z, xB.x, a2.x); a2.y = fmaf(wB.z, xB.y, a2.y);
            a3.x = fmaf(wB.w, xB.x, a3.x); a3.y = fmaf(wB.w, xB.y, a3.y);
            d0 += wB.x; d1 += wB.y; d2 += wB.z; d3 += wB.w;
        }
        if (j < end) {
            int s0 = srcs[j];
            float4 wA = w4[j];
            float2 xA = *(const float2*)&x[(size_t)s0 * 128 + 2 * l];
            a0.x = fmaf(wA.x, xA.x, a0.x); a0.y = fmaf(wA.x, xA.y, a0.y);
            a1.x = fmaf(wA.y, xA.x, a1.x); a1.y = fmaf(wA.y, xA.y, a1.y);
            a2.x = fmaf(wA.z, xA.x, a2.x); a2.y = fmaf(wA.z, xA.y, a2.y);
            a3.x = fmaf(wA.w, xA.x, a3.x); a3.y = fmaf(wA.w, xA.y, a3.y);
            d0 += wA.x; d1 += wA.y; d2 += wA.z; d3 += wA.w;
        }
        float i0 = d0 > 0.f ? 1.f / d0 : 0.f;
        float i1 = d1 > 0.f ? 1.f / d1 : 0.f;
        float i2 = d2 > 0.f ? 1.f / d2 : 0.f;
        float i3 = d3 > 0.f ? 1.f / d3 : 0.f;
        *(float2*)&xs[r * 512 + 0 * 128 + 2 * l] = make_float2(a0.x * i0, a0.y * i0);
        *(float2*)&xs[r * 512 + 1 * 128 + 2 * l] = make_float2(a1.x * i1, a1.y * i1);
        *(float2*)&xs[r * 512 + 2 * 128 + 2 * l] = make_float2(a2.x * i2, a2.y * i2);
        *(float2*)&xs[r * 512 + 3 * 128 + 2 * l] = make_float2(a3.x * i3, a3.y * i3);
    }
    __syncthreads();
    float acc[RPB];
#pragma unroll
    for (int r = 0; r < RPB; ++r) acc[r] = 0.f;
    for (int k = 0; k < 128; k += 4) {
        float w0 = W1[(k + 0) * 256 + t];
        float w1 = W1[(k + 1) * 256 + t];
        float w2 = W1[(k + 2) * 256 + t];
        float w3 = W1[(k + 3) * 256 + t];
        int base = wv * 128 + k;
#pragma unroll
        for (int r = 0; r < RPB; ++r) {
            float4 xv = *(const float4*)&xs[r * 512 + base];
            acc[r] = fmaf(xv.x, w0, acc[r]);
            acc[r] = fmaf(xv.y, w1, acc[r]);
            acc[r] = fmaf(xv.z, w2, acc[r]);
            acc[r] = fmaf(xv.w, w3, acc[r]);
        }
    }
    float bv = b1[t];
#pragma unroll
    for (int r = 0; r < RPB; ++r) {
        float o = acc[r] + bv;
        o = o > 0.f ? o : (__expf(o) - 1.f);
        elu1[(size_t)(n0 + r) * 256 + t] = o;
    }
}

// ---------------- layer 2 ----------------
__global__ void k_gemm2(const float* __restrict__ xin, const float* __restrict__ W,
                        float* __restrict__ h2) {
    __shared__ float xs[32 * 257];
    int t = threadIdx.x;
    int n0 = blockIdx.x * 32;
    for (int i = 0; i < 8; ++i) {
        int f = i * 256 + t;
        int row = f >> 6;
        int col = (f & 63) * 4;
        float4 v = make_float4(0.f, 0.f, 0.f, 0.f);
        if (n0 + row < NN) v = ((const float4*)xin)[(size_t)n0 * 64 + f];
        xs[row * 257 + col + 0] = v.x;
        xs[row * 257 + col + 1] = v.y;
        xs[row * 257 + col + 2] = v.z;
        xs[row * 257 + col + 3] = v.w;
    }
    __syncthreads();
    int nl = t & 31;
    int cg = t >> 5;
    int c0 = cg * 5;
    float acc[5] = {0, 0, 0, 0, 0};
    for (int k = 0; k < 256; ++k) {
        float xv = xs[nl * 257 + k];
#pragma unroll
        for (int i = 0; i < 5; ++i) acc[i] = fmaf(xv, W[k * 40 + c0 + i], acc[i]);
    }
    int node = n0 + nl;
    if (node < NN) {
#pragma unroll
        for (int i = 0; i < 5; ++i) h2[(size_t)node * 40 + c0 + i] = acc[i];
    }
}

__global__ void k_elr2(const float* __restrict__ h2, const float* __restrict__ al,
                       const float* __restrict__ ar, float* __restrict__ el,
                       float* __restrict__ er) {
    int nd = blockIdx.x * 256 + threadIdx.x;
    if (nd < NN) {
        float a = 0.f, b = 0.f;
        for (int c = 0; c < NCLS; ++c) {
            float v = h2[(size_t)nd * NCLS + c];
            a = fmaf(v, al[c], a);
            b = fmaf(v, ar[c], b);
        }
        el[nd] = a;
        er[nd] = b;
    }
}

__global__ void k_w2(const int* __restrict__ src, const int* __restrict__ dst,
                     const int* __restrict__ slot, const float* __restrict__ el2,
                     const float* __restrict__ er2, float* __restrict__ w2s) {
    int e = blockIdx.x * 256 + threadIdx.x;
    if (e >= NE) return;
    float ee = el2[src[e]] + er2[dst[e]];
    ee = ee > 0.f ? ee : 0.2f * ee;
    w2s[slot[e]] = __expf(ee);
}

// final aggregation: wave per dst, lanes 0..39 carry features
__global__ void k_agg2b(const float* __restrict__ h2, const float* __restrict__ w2s,
                        const float* __restrict__ b2, const int* __restrict__ indptr,
                        const int* __restrict__ srcs, float* __restrict__ out) {
    int t = threadIdx.x;
    int wv = t >> 6, l = t & 63;
    int d = blockIdx.x * 4 + wv;
    int beg = indptr[d], end = indptr[d + 1];
    float acc = 0.f, den = 0.f;
    int j = beg;
    for (; j + 1 < end; j += 2) {
        int s0 = srcs[j], s1 = srcs[j + 1];
        float w0 = w2s[j], w1 = w2s[j + 1];
        float v0 = 0.f, v1 = 0.f;
        if (l < NCLS) {
            v0 = h2[(size_t)s0 * NCLS + l];
            v1 = h2[(size_t)s1 * NCLS + l];
        }
        acc = fmaf(w0, v0, acc);
        acc = fmaf(w1, v1, acc);
        den += w0 + w1;
    }
    if (j < end) {
        int s0 = srcs[j];
        float w0 = w2s[j];
        float v0 = (l < NCLS) ? h2[(size_t)s0 * NCLS + l] : 0.f;
        acc = fmaf(w0, v0, acc);
        den += w0;
    }
    if (l < NCLS) {
        float o = (den > 0.f ? acc / den : 0.f) + b2[l];
        out[(size_t)d * NCLS + l] = o;
    }
}

extern "C" void kernel_launch(void* const* d_in, const int* in_sizes, int n_in,
                              void* d_out, int out_size, void* d_ws, size_t ws_size,
                              hipStream_t stream) {
    const float* x   = (const float*)d_in[0];
    const int*   src = (const int*)d_in[1];
    const int*   dst = (const int*)d_in[2];
    const float* W1  = (const float*)d_in[3];
    const float* al1 = (const float*)d_in[4];
    const float* ar1 = (const float*)d_in[5];
    const float* b1  = (const float*)d_in[6];
    const float* W2  = (const float*)d_in[7];
    const float* al2 = (const float*)d_in[8];
    const float* ar2 = (const float*)d_in[9];
    const float* b2  = (const float*)d_in[10];
    float* out = (float*)d_out;

    float* ws = (float*)d_ws;
    size_t off = 0;
    float* elu1 = ws + off; off += (size_t)NN * HID;      // 12.8M
    float* h2   = ws + off; off += (size_t)NN * NCLS;     // 2M
    float* el1  = ws + off; off += (size_t)NN * 4;
    float* er1  = ws + off; off += (size_t)NN * 4;
    float* el2  = ws + off; off += NN;
    float* er2  = ws + off; off += NN;
    float* wel  = ws + off; off += 512;
    float* wer  = ws + off; off += 512;
    float* w4   = ws + off; off += (size_t)NE * 4;        // float4-aligned
    float* w2s  = ws + off; off += NE;
    int* counts = (int*)(ws + off);
    int* indptr = counts + NN;
    int* fill   = indptr + NN + 1;
    int* srcs   = fill + NN;
    int* slot   = srcs + NE;

    hipMemsetAsync(counts, 0, NN * sizeof(int), stream);
    hipMemsetAsync(fill, 0, NN * sizeof(int), stream);

    k_count<<<(NE + 255) / 256, 256, 0, stream>>>(dst, counts);
    k_scan<<<1, 1024, 0, stream>>>(counts, indptr);
    k_scatter<<<(NE + 255) / 256, 256, 0, stream>>>(src, dst, indptr, fill, srcs, slot);

    k_prew<<<1, 512, 0, stream>>>(W1, al1, ar1, wel, wer);
    k_elr1x<<<(NN + 63) / 64, 256, 0, stream>>>(x, wel, wer, el1, er1);
    k_w1<<<(NE + 255) / 256, 256, 0, stream>>>(src, dst, slot, el1, er1, (float4*)w4);
    k_fused1<<<NN / RPB, 256, 0, stream>>>(x, W1, b1, indptr, srcs, (const float4*)w4, elu1);

    k_gemm2<<<(NN + 31) / 32, 256, 0, stream>>>(elu1, W2, h2);
    k_elr2<<<(NN + 255) / 256, 256, 0, stream>>>(h2, al2, ar2, el2, er2);
    k_w2<<<(NE + 255) / 256, 256, 0, stream>>>(src, dst, slot, el2, er2, w2s);
    k_agg2b<<<NN / 4, 256, 0, stream>>>(h2, w2s, b2, indptr, srcs, out);
}

// Round 3
// 490.899 us; speedup vs baseline: 1.1821x; 1.0220x over previous
//
#include <hip/hip_runtime.h>

#define NN 50000
#define NE 800000
#define HID 256
#define NCLS 40

// ---------------- CSR build ----------------
__global__ void k_count(const int* __restrict__ dst, int* __restrict__ counts) {
    int e = blockIdx.x * 256 + threadIdx.x;
    if (e < NE) atomicAdd(&counts[dst[e]], 1);
}

__global__ void k_scan(const int* __restrict__ counts, int* __restrict__ indptr) {
    __shared__ int part[1024];
    int t = threadIdx.x;
    const int n = NN;
    const int chunk = (n + 1023) / 1024;
    int b = t * chunk;
    int e = b + chunk; if (e > n) e = n;
    int s = 0;
    for (int i = b; i < e; ++i) s += counts[i];
    part[t] = s;
    __syncthreads();
    for (int off = 1; off < 1024; off <<= 1) {
        int v = (t >= off) ? part[t - off] : 0;
        __syncthreads();
        part[t] += v;
        __syncthreads();
    }
    int run = (t > 0) ? part[t - 1] : 0;
    for (int i = b; i < e; ++i) { indptr[i] = run; run += counts[i]; }
    if (t == 1023) indptr[n] = part[1023];
}

__global__ void k_scatter(const int* __restrict__ src, const int* __restrict__ dst,
                          const int* __restrict__ indptr, int* __restrict__ fill,
                          int* __restrict__ srcs) {
    int e = blockIdx.x * 256 + threadIdx.x;
    if (e < NE) {
        int d = dst[e];
        int pos = atomicAdd(&fill[d], 1);
        srcs[indptr[d] + pos] = src[e];
    }
}

// ---------------- layer 1 ----------------
__global__ void k_prew(const float* __restrict__ W1, const float* __restrict__ al,
                       const float* __restrict__ ar, float* __restrict__ wel,
                       float* __restrict__ wer) {
    int t = threadIdx.x;           // 512 threads
    int k = t >> 2, h = t & 3;
    float a = 0.f, b = 0.f;
    for (int dd = 0; dd < 64; ++dd) {
        float w = W1[k * 256 + h * 64 + dd];
        a = fmaf(w, al[h * 64 + dd], a);
        b = fmaf(w, ar[h * 64 + dd], b);
    }
    wel[k * 4 + h] = a;
    wer[k * 4 + h] = b;
}

// el1/er1[N,4] = x @ wel / x @ wer ; 64 nodes per block
__global__ void k_elr1x(const float* __restrict__ x, const float* __restrict__ wel,
                        const float* __restrict__ wer, float* __restrict__ el1,
                        float* __restrict__ er1) {
    __shared__ float xs[64 * 129];
    __shared__ float wels[512], wers[512];
    int t = threadIdx.x;
    int n0 = blockIdx.x * 64;
    wels[t] = wel[t]; wels[256 + t] = wel[256 + t];
    wers[t] = wer[t]; wers[256 + t] = wer[256 + t];
    for (int i = 0; i < 8; ++i) {
        int f = i * 256 + t;
        int row = f >> 5;
        int col4 = (f & 31) * 4;
        float4 v = make_float4(0.f, 0.f, 0.f, 0.f);
        if (n0 + row < NN) v = ((const float4*)x)[(size_t)n0 * 32 + f];
        xs[row * 129 + col4 + 0] = v.x;
        xs[row * 129 + col4 + 1] = v.y;
        xs[row * 129 + col4 + 2] = v.z;
        xs[row * 129 + col4 + 3] = v.w;
    }
    __syncthreads();
    int node = t & 63;
    int h = t >> 6;                  // uniform per wave
    float a = 0.f, b = 0.f;
    for (int k = 0; k < 128; ++k) {
        float xv = xs[node * 129 + k];
        a = fmaf(xv, wels[k * 4 + h], a);
        b = fmaf(xv, wers[k * 4 + h], b);
    }
    if (n0 + node < NN) {
        el1[(size_t)(n0 + node) * 4 + h] = a;
        er1[(size_t)(n0 + node) * 4 + h] = b;
    }
}

// node-parallel: compute per-edge weights in CSR order AND normalize by the
// per-(node,head) sum, so downstream gathers need no denominator.
__global__ void k_w1n(const int* __restrict__ indptr, const int* __restrict__ srcs,
                      const float* __restrict__ el1, const float* __restrict__ er1,
                      float4* __restrict__ w4) {
    int d = blockIdx.x * 256 + threadIdx.x;
    if (d >= NN) return;
    float4 rd = *(const float4*)&er1[(size_t)d * 4];
    int beg = indptr[d], end = indptr[d + 1];
    float s0 = 0.f, s1 = 0.f, s2 = 0.f, s3 = 0.f;
    for (int j = beg; j < end; ++j) {
        int s = srcs[j];
        float4 ls = *(const float4*)&el1[(size_t)s * 4];
        float e0 = ls.x + rd.x, e1 = ls.y + rd.y, e2 = ls.z + rd.z, e3 = ls.w + rd.w;
        e0 = e0 > 0.f ? e0 : 0.2f * e0;
        e1 = e1 > 0.f ? e1 : 0.2f * e1;
        e2 = e2 > 0.f ? e2 : 0.2f * e2;
        e3 = e3 > 0.f ? e3 : 0.2f * e3;
        float4 w = make_float4(__expf(e0), __expf(e1), __expf(e2), __expf(e3));
        w4[j] = w;
        s0 += w.x; s1 += w.y; s2 += w.z; s3 += w.w;
    }
    float i0 = s0 > 0.f ? 1.f / s0 : 0.f;
    float i1 = s1 > 0.f ? 1.f / s1 : 0.f;
    float i2 = s2 > 0.f ? 1.f / s2 : 0.f;
    float i3 = s3 > 0.f ? 1.f / s3 : 0.f;
    for (int j = beg; j < end; ++j) {
        float4 w = w4[j];
        w4[j] = make_float4(w.x * i0, w.y * i1, w.z * i2, w.w * i3);
    }
}

// fused: per-dst weighted x-gather (4 heads, pre-normalized) -> LDS -> @W1 + bias + ELU
#define RPB 8
__global__ void k_fused1(const float* __restrict__ x, const float* __restrict__ W1,
                         const float* __restrict__ b1, const int* __restrict__ indptr,
                         const int* __restrict__ srcs, const float4* __restrict__ w4,
                         float* __restrict__ elu1) {
    __shared__ float xs[RPB * 512];   // 16 KB -> 8 blocks/CU
    int t = threadIdx.x;
    int wv = t >> 6, l = t & 63;
    int n0 = blockIdx.x * RPB;
    for (int rr = 0; rr < RPB / 4; ++rr) {
        int r = rr * 4 + wv;
        int d = n0 + r;
        float2 a0 = {0.f, 0.f}, a1 = {0.f, 0.f}, a2 = {0.f, 0.f}, a3 = {0.f, 0.f};
        int beg = indptr[d], end = indptr[d + 1];
        int j = beg;
        for (; j + 1 < end; j += 2) {
            int s0 = srcs[j], s1 = srcs[j + 1];
            float4 wA = w4[j], wB = w4[j + 1];
            float2 xA = *(const float2*)&x[(size_t)s0 * 128 + 2 * l];
            float2 xB = *(const float2*)&x[(size_t)s1 * 128 + 2 * l];
            a0.x = fmaf(wA.x, xA.x, a0.x); a0.y = fmaf(wA.x, xA.y, a0.y);
            a1.x = fmaf(wA.y, xA.x, a1.x); a1.y = fmaf(wA.y, xA.y, a1.y);
            a2.x = fmaf(wA.z, xA.x, a2.x); a2.y = fmaf(wA.z, xA.y, a2.y);
            a3.x = fmaf(wA.w, xA.x, a3.x); a3.y = fmaf(wA.w, xA.y, a3.y);
            a0.x = fmaf(wB.x, xB.x, a0.x); a0.y = fmaf(wB.x, xB.y, a0.y);
            a1.x = fmaf(wB.y, xB.x, a1.x); a1.y = fmaf(wB.y, xB.y, a1.y);
            a2.x = fmaf(wB.z, xB.x, a2.x); a2.y = fmaf(wB.z, xB.y, a2.y);
            a3.x = fmaf(wB.w, xB.x, a3.x); a3.y = fmaf(wB.w, xB.y, a3.y);
        }
        if (j < end) {
            int s0 = srcs[j];
            float4 wA = w4[j];
            float2 xA = *(const float2*)&x[(size_t)s0 * 128 + 2 * l];
            a0.x = fmaf(wA.x, xA.x, a0.x); a0.y = fmaf(wA.x, xA.y, a0.y);
            a1.x = fmaf(wA.y, xA.x, a1.x); a1.y = fmaf(wA.y, xA.y, a1.y);
            a2.x = fmaf(wA.z, xA.x, a2.x); a2.y = fmaf(wA.z, xA.y, a2.y);
            a3.x = fmaf(wA.w, xA.x, a3.x); a3.y = fmaf(wA.w, xA.y, a3.y);
        }
        *(float2*)&xs[r * 512 + 0 * 128 + 2 * l] = a0;
        *(float2*)&xs[r * 512 + 1 * 128 + 2 * l] = a1;
        *(float2*)&xs[r * 512 + 2 * 128 + 2 * l] = a2;
        *(float2*)&xs[r * 512 + 3 * 128 + 2 * l] = a3;
    }
    __syncthreads();
    float acc[RPB];
#pragma unroll
    for (int r = 0; r < RPB; ++r) acc[r] = 0.f;
    for (int k = 0; k < 128; k += 4) {
        float w0 = W1[(k + 0) * 256 + t];
        float w1 = W1[(k + 1) * 256 + t];
        float w2 = W1[(k + 2) * 256 + t];
        float w3 = W1[(k + 3) * 256 + t];
        int base = wv * 128 + k;
#pragma unroll
        for (int r = 0; r < RPB; ++r) {
            float4 xv = *(const float4*)&xs[r * 512 + base];
            acc[r] = fmaf(xv.x, w0, acc[r]);
            acc[r] = fmaf(xv.y, w1, acc[r]);
            acc[r] = fmaf(xv.z, w2, acc[r]);
            acc[r] = fmaf(xv.w, w3, acc[r]);
        }
    }
    float bv = b1[t];
#pragma unroll
    for (int r = 0; r < RPB; ++r) {
        float o = acc[r] + bv;
        o = o > 0.f ? o : (__expf(o) - 1.f);
        elu1[(size_t)(n0 + r) * 256 + t] = o;
    }
}

// ---------------- layer 2 ----------------
__global__ void k_w2t(const float* __restrict__ W2, float* __restrict__ W2T) {
    int t = threadIdx.x;   // 256
    for (int c = 0; c < NCLS; ++c) W2T[c * 256 + t] = W2[t * 40 + c];
}

__global__ void k_gemm2(const float* __restrict__ xin, const float* __restrict__ W2T,
                        float* __restrict__ h2) {
    __shared__ float xs[32 * 257];
    int t = threadIdx.x;
    int n0 = blockIdx.x * 32;
    for (int i = 0; i < 8; ++i) {
        int f = i * 256 + t;
        int row = f >> 6;
        int col = (f & 63) * 4;
        float4 v = make_float4(0.f, 0.f, 0.f, 0.f);
        if (n0 + row < NN) v = ((const float4*)xin)[(size_t)n0 * 64 + f];
        xs[row * 257 + col + 0] = v.x;
        xs[row * 257 + col + 1] = v.y;
        xs[row * 257 + col + 2] = v.z;
        xs[row * 257 + col + 3] = v.w;
    }
    __syncthreads();
    int nl = t & 31;
    int cg = t >> 5;
    int c0 = cg * 5;
    float acc[5] = {0, 0, 0, 0, 0};
    for (int k = 0; k < 256; k += 4) {
        float x0 = xs[nl * 257 + k + 0];
        float x1 = xs[nl * 257 + k + 1];
        float x2 = xs[nl * 257 + k + 2];
        float x3 = xs[nl * 257 + k + 3];
#pragma unroll
        for (int i = 0; i < 5; ++i) {
            float4 w = *(const float4*)&W2T[(c0 + i) * 256 + k];
            acc[i] = fmaf(x0, w.x, acc[i]);
            acc[i] = fmaf(x1, w.y, acc[i]);
            acc[i] = fmaf(x2, w.z, acc[i]);
            acc[i] = fmaf(x3, w.w, acc[i]);
        }
    }
    int node = n0 + nl;
    if (node < NN) {
#pragma unroll
        for (int i = 0; i < 5; ++i) h2[(size_t)node * 40 + c0 + i] = acc[i];
    }
}

__global__ void k_elr2(const float* __restrict__ h2, const float* __restrict__ al,
                       const float* __restrict__ ar, float* __restrict__ el,
                       float* __restrict__ er) {
    int nd = blockIdx.x * 256 + threadIdx.x;
    if (nd < NN) {
        float a = 0.f, b = 0.f;
        for (int c = 0; c < NCLS; ++c) {
            float v = h2[(size_t)nd * NCLS + c];
            a = fmaf(v, al[c], a);
            b = fmaf(v, ar[c], b);
        }
        el[nd] = a;
        er[nd] = b;
    }
}

__global__ void k_w2n(const int* __restrict__ indptr, const int* __restrict__ srcs,
                      const float* __restrict__ el2, const float* __restrict__ er2,
                      float* __restrict__ w2s) {
    int d = blockIdx.x * 256 + threadIdx.x;
    if (d >= NN) return;
    float rd = er2[d];
    int beg = indptr[d], end = indptr[d + 1];
    float acc = 0.f;
    for (int j = beg; j < end; ++j) {
        float e = el2[srcs[j]] + rd;
        e = e > 0.f ? e : 0.2f * e;
        float w = __expf(e);
        w2s[j] = w;
        acc += w;
    }
    float inv = acc > 0.f ? 1.f / acc : 0.f;
    for (int j = beg; j < end; ++j) w2s[j] *= inv;
}

// final aggregation: wave per dst, lanes 0..39 carry features (weights pre-normalized)
__global__ void k_agg2b(const float* __restrict__ h2, const float* __restrict__ w2s,
                        const float* __restrict__ b2, const int* __restrict__ indptr,
                        const int* __restrict__ srcs, float* __restrict__ out) {
    int t = threadIdx.x;
    int wv = t >> 6, l = t & 63;
    int d = blockIdx.x * 4 + wv;
    int beg = indptr[d], end = indptr[d + 1];
    float acc = 0.f;
    int j = beg;
    for (; j + 1 < end; j += 2) {
        int s0 = srcs[j], s1 = srcs[j + 1];
        float w0 = w2s[j], w1 = w2s[j + 1];
        float v0 = 0.f, v1 = 0.f;
        if (l < NCLS) {
            v0 = h2[(size_t)s0 * NCLS + l];
            v1 = h2[(size_t)s1 * NCLS + l];
        }
        acc = fmaf(w0, v0, acc);
        acc = fmaf(w1, v1, acc);
    }
    if (j < end) {
        int s0 = srcs[j];
        float w0 = w2s[j];
        float v0 = (l < NCLS) ? h2[(size_t)s0 * NCLS + l] : 0.f;
        acc = fmaf(w0, v0, acc);
    }
    if (l < NCLS) out[(size_t)d * NCLS + l] = acc + b2[l];
}

extern "C" void kernel_launch(void* const* d_in, const int* in_sizes, int n_in,
                              void* d_out, int out_size, void* d_ws, size_t ws_size,
                              hipStream_t stream) {
    const float* x   = (const float*)d_in[0];
    const int*   src = (const int*)d_in[1];
    const int*   dst = (const int*)d_in[2];
    const float* W1  = (const float*)d_in[3];
    const float* al1 = (const float*)d_in[4];
    const float* ar1 = (const float*)d_in[5];
    const float* b1  = (const float*)d_in[6];
    const float* W2  = (const float*)d_in[7];
    const float* al2 = (const float*)d_in[8];
    const float* ar2 = (const float*)d_in[9];
    const float* b2  = (const float*)d_in[10];
    float* out = (float*)d_out;

    float* ws = (float*)d_ws;
    size_t off = 0;
    float* elu1 = ws + off; off += (size_t)NN * HID;      // 12.8M
    float* h2   = ws + off; off += (size_t)NN * NCLS;     // 2M
    float* el1  = ws + off; off += (size_t)NN * 4;
    float* er1  = ws + off; off += (size_t)NN * 4;
    float* el2  = ws + off; off += NN;
    float* er2  = ws + off; off += NN;
    float* wel  = ws + off; off += 512;
    float* wer  = ws + off; off += 512;
    float* w2t  = ws + off; off += (size_t)NCLS * 256;
    float* w4   = ws + off; off += (size_t)NE * 4;        // 16B-aligned
    float* w2s  = ws + off; off += NE;
    int* counts = (int*)(ws + off);
    int* indptr = counts + NN;
    int* fill   = indptr + NN + 1;
    int* srcs   = fill + NN;

    hipMemsetAsync(counts, 0, NN * sizeof(int), stream);
    hipMemsetAsync(fill, 0, NN * sizeof(int), stream);

    k_count<<<(NE + 255) / 256, 256, 0, stream>>>(dst, counts);
    k_scan<<<1, 1024, 0, stream>>>(counts, indptr);
    k_scatter<<<(NE + 255) / 256, 256, 0, stream>>>(src, dst, indptr, fill, srcs);

    k_prew<<<1, 512, 0, stream>>>(W1, al1, ar1, wel, wer);
    k_elr1x<<<(NN + 63) / 64, 256, 0, stream>>>(x, wel, wer, el1, er1);
    k_w1n<<<(NN + 255) / 256, 256, 0, stream>>>(indptr, srcs, el1, er1, (float4*)w4);
    k_fused1<<<NN / RPB, 256, 0, stream>>>(x, W1, b1, indptr, srcs, (const float4*)w4, elu1);

    k_w2t<<<1, 256, 0, stream>>>(W2, w2t);
    k_gemm2<<<(NN + 31) / 32, 256, 0, stream>>>(elu1, w2t, h2);
    k_elr2<<<(NN + 255) / 256, 256, 0, stream>>>(h2, al2, ar2, el2, er2);
    k_w2n<<<(NN + 255) / 256, 256, 0, stream>>>(indptr, srcs, el2, er2, w2s);
    k_agg2b<<<NN / 4, 256, 0, stream>>>(h2, w2s, b2, indptr, srcs, out);
}

// Round 4
// 403.871 us; speedup vs baseline: 1.4369x; 1.2155x over previous
//
#include <hip/hip_runtime.h>

#define NN 50000
#define NE 800000
#define HID 256
#define NCLS 40

// ---------------- CSR build ----------------
__global__ void k_count(const int* __restrict__ dst, int* __restrict__ counts) {
    int e = blockIdx.x * 256 + threadIdx.x;
    if (e < NE) atomicAdd(&counts[dst[e]], 1);
}

// hierarchical scan: A) per-block exclusive scan + block sums
__global__ void k_scanA(const int* __restrict__ counts, int* __restrict__ indptr,
                        int* __restrict__ bsum) {
    __shared__ int sh[256];
    int t = threadIdx.x;
    int idx = blockIdx.x * 256 + t;
    int c = idx < NN ? counts[idx] : 0;
    sh[t] = c;
    __syncthreads();
    for (int off = 1; off < 256; off <<= 1) {
        int v = (t >= off) ? sh[t - off] : 0;
        __syncthreads();
        sh[t] += v;
        __syncthreads();
    }
    if (idx < NN) indptr[idx] = sh[t] - c;       // block-local exclusive
    if (t == 255) bsum[blockIdx.x] = sh[255];    // block total
}

// B) scan the 196 block sums (one block)
__global__ void k_scanB(int* __restrict__ bsum, int nb) {
    __shared__ int sh[256];
    int t = threadIdx.x;
    int c = t < nb ? bsum[t] : 0;
    sh[t] = c;
    __syncthreads();
    for (int off = 1; off < 256; off <<= 1) {
        int v = (t >= off) ? sh[t - off] : 0;
        __syncthreads();
        sh[t] += v;
        __syncthreads();
    }
    if (t < nb) bsum[t] = sh[t] - c;             // exclusive
}

// C) add block offsets, zero fill, set sentinel
__global__ void k_scanC(int* __restrict__ indptr, const int* __restrict__ bsum,
                        int* __restrict__ fill) {
    int idx = blockIdx.x * 256 + threadIdx.x;
    if (idx < NN) {
        indptr[idx] += bsum[idx >> 8];
        fill[idx] = 0;
    }
    if (idx == 0) indptr[NN] = NE;
}

__global__ void k_scatter(const int* __restrict__ src, const int* __restrict__ dst,
                          const int* __restrict__ indptr, int* __restrict__ fill,
                          int* __restrict__ srcs) {
    int e = blockIdx.x * 256 + threadIdx.x;
    if (e < NE) {
        int d = dst[e];
        int pos = atomicAdd(&fill[d], 1);
        srcs[indptr[d] + pos] = src[e];
    }
}

// ---------------- tiny precompute: wel/wer + W2 transpose ----------------
__global__ void k_prep(const float* __restrict__ W1, const float* __restrict__ al,
                       const float* __restrict__ ar, const float* __restrict__ W2,
                       float* __restrict__ wel, float* __restrict__ wer,
                       float* __restrict__ W2T) {
    int t = threadIdx.x;           // 512 threads
    int k = t >> 2, h = t & 3;
    float a = 0.f, b = 0.f;
    for (int dd = 0; dd < 64; ++dd) {
        float w = W1[k * 256 + h * 64 + dd];
        a = fmaf(w, al[h * 64 + dd], a);
        b = fmaf(w, ar[h * 64 + dd], b);
    }
    wel[k * 4 + h] = a;
    wer[k * 4 + h] = b;
    for (int i = t; i < 256 * NCLS; i += 512) {
        int c = i >> 8, kk = i & 255;
        W2T[i] = W2[kk * 40 + c];
    }
}

// el1/er1[N,4] = x @ wel / x @ wer ; 64 nodes per block
__global__ void k_elr1x(const float* __restrict__ x, const float* __restrict__ wel,
                        const float* __restrict__ wer, float* __restrict__ el1,
                        float* __restrict__ er1) {
    __shared__ float xs[64 * 129];
    __shared__ float wels[512], wers[512];
    int t = threadIdx.x;
    int n0 = blockIdx.x * 64;
    wels[t] = wel[t]; wels[256 + t] = wel[256 + t];
    wers[t] = wer[t]; wers[256 + t] = wer[256 + t];
    for (int i = 0; i < 8; ++i) {
        int f = i * 256 + t;
        int row = f >> 5;
        int col4 = (f & 31) * 4;
        float4 v = make_float4(0.f, 0.f, 0.f, 0.f);
        if (n0 + row < NN) v = ((const float4*)x)[(size_t)n0 * 32 + f];
        xs[row * 129 + col4 + 0] = v.x;
        xs[row * 129 + col4 + 1] = v.y;
        xs[row * 129 + col4 + 2] = v.z;
        xs[row * 129 + col4 + 3] = v.w;
    }
    __syncthreads();
    int node = t & 63;
    int h = t >> 6;                  // uniform per wave
    float a = 0.f, b = 0.f;
    for (int k = 0; k < 128; ++k) {
        float xv = xs[node * 129 + k];
        a = fmaf(xv, wels[k * 4 + h], a);
        b = fmaf(xv, wers[k * 4 + h], b);
    }
    if (n0 + node < NN) {
        el1[(size_t)(n0 + node) * 4 + h] = a;
        er1[(size_t)(n0 + node) * 4 + h] = b;
    }
}

// wave-per-dst: per-edge normalized weights (lane-parallel over edges)
__global__ void k_w1n(const int* __restrict__ indptr, const int* __restrict__ srcs,
                      const float* __restrict__ el1, const float* __restrict__ er1,
                      float4* __restrict__ w4) {
    int t = threadIdx.x;
    int wv = t >> 6, l = t & 63;
    int d = blockIdx.x * 4 + wv;
    float4 rd = *(const float4*)&er1[(size_t)d * 4];
    int beg = indptr[d], end = indptr[d + 1];
    int j0 = beg + l;
    bool has = j0 < end;
    float4 wf = make_float4(0.f, 0.f, 0.f, 0.f);
    float s0 = 0.f, s1 = 0.f, s2 = 0.f, s3 = 0.f;
    if (has) {
        float4 ls = *(const float4*)&el1[(size_t)srcs[j0] * 4];
        float e0 = ls.x + rd.x, e1 = ls.y + rd.y, e2 = ls.z + rd.z, e3 = ls.w + rd.w;
        e0 = e0 > 0.f ? e0 : 0.2f * e0;
        e1 = e1 > 0.f ? e1 : 0.2f * e1;
        e2 = e2 > 0.f ? e2 : 0.2f * e2;
        e3 = e3 > 0.f ? e3 : 0.2f * e3;
        wf = make_float4(__expf(e0), __expf(e1), __expf(e2), __expf(e3));
        s0 = wf.x; s1 = wf.y; s2 = wf.z; s3 = wf.w;
    }
    for (int j = j0 + 64; j < end; j += 64) {       // deg > 64 fallback
        float4 ls = *(const float4*)&el1[(size_t)srcs[j] * 4];
        float e0 = ls.x + rd.x, e1 = ls.y + rd.y, e2 = ls.z + rd.z, e3 = ls.w + rd.w;
        e0 = e0 > 0.f ? e0 : 0.2f * e0;
        e1 = e1 > 0.f ? e1 : 0.2f * e1;
        e2 = e2 > 0.f ? e2 : 0.2f * e2;
        e3 = e3 > 0.f ? e3 : 0.2f * e3;
        float4 w = make_float4(__expf(e0), __expf(e1), __expf(e2), __expf(e3));
        w4[j] = w;
        s0 += w.x; s1 += w.y; s2 += w.z; s3 += w.w;
    }
#pragma unroll
    for (int off = 32; off > 0; off >>= 1) {
        s0 += __shfl_xor(s0, off);
        s1 += __shfl_xor(s1, off);
        s2 += __shfl_xor(s2, off);
        s3 += __shfl_xor(s3, off);
    }
    float i0 = s0 > 0.f ? 1.f / s0 : 0.f;
    float i1 = s1 > 0.f ? 1.f / s1 : 0.f;
    float i2 = s2 > 0.f ? 1.f / s2 : 0.f;
    float i3 = s3 > 0.f ? 1.f / s3 : 0.f;
    if (has) w4[j0] = make_float4(wf.x * i0, wf.y * i1, wf.z * i2, wf.w * i3);
    for (int j = j0 + 64; j < end; j += 64) {
        float4 w = w4[j];
        w4[j] = make_float4(w.x * i0, w.y * i1, w.z * i2, w.w * i3);
    }
}

// fused: half-wave-per-edge weighted x-gather -> LDS -> @W1 + bias + ELU
#define RPB 8
#define ACCUM(WV, XV) \
    a0.x = fmaf(WV.x, XV.x, a0.x); a0.y = fmaf(WV.x, XV.y, a0.y); \
    a0.z = fmaf(WV.x, XV.z, a0.z); a0.w = fmaf(WV.x, XV.w, a0.w); \
    a1.x = fmaf(WV.y, XV.x, a1.x); a1.y = fmaf(WV.y, XV.y, a1.y); \
    a1.z = fmaf(WV.y, XV.z, a1.z); a1.w = fmaf(WV.y, XV.w, a1.w); \
    a2.x = fmaf(WV.z, XV.x, a2.x); a2.y = fmaf(WV.z, XV.y, a2.y); \
    a2.z = fmaf(WV.z, XV.z, a2.z); a2.w = fmaf(WV.z, XV.w, a2.w); \
    a3.x = fmaf(WV.w, XV.x, a3.x); a3.y = fmaf(WV.w, XV.y, a3.y); \
    a3.z = fmaf(WV.w, XV.z, a3.z); a3.w = fmaf(WV.w, XV.w, a3.w);

__global__ void k_fused1(const float* __restrict__ x, const float* __restrict__ W1,
                         const float* __restrict__ b1, const int* __restrict__ indptr,
                         const int* __restrict__ srcs, const float4* __restrict__ w4,
                         float* __restrict__ elu1) {
    __shared__ float xs[RPB * 512];   // 16 KB
    int t = threadIdx.x;
    int wv = t >> 6, l = t & 63;
    int half = l >> 5, il = l & 31;
    int n0 = blockIdx.x * RPB;
    for (int rr = 0; rr < RPB / 4; ++rr) {
        int r = rr * 4 + wv;
        int d = n0 + r;
        int beg = indptr[d], end = indptr[d + 1];
        float4 a0 = {0,0,0,0}, a1 = {0,0,0,0}, a2 = {0,0,0,0}, a3 = {0,0,0,0};
        for (int j = beg; j < end; j += 4) {
            int jA = j + half;
            int jB = j + 2 + half;
            bool vA = jA < end, vB = jB < end;
            int sA = vA ? srcs[jA] : 0;
            int sB = vB ? srcs[jB] : 0;
            float4 wA = vA ? w4[jA] : make_float4(0.f, 0.f, 0.f, 0.f);
            float4 wB = vB ? w4[jB] : make_float4(0.f, 0.f, 0.f, 0.f);
            float4 xA = ((const float4*)(x + (size_t)sA * 128))[il];
            float4 xB = ((const float4*)(x + (size_t)sB * 128))[il];
            ACCUM(wA, xA)
            ACCUM(wB, xB)
        }
        // cross-half reduce (edge-pair partials)
        a0.x += __shfl_xor(a0.x, 32); a0.y += __shfl_xor(a0.y, 32);
        a0.z += __shfl_xor(a0.z, 32); a0.w += __shfl_xor(a0.w, 32);
        a1.x += __shfl_xor(a1.x, 32); a1.y += __shfl_xor(a1.y, 32);
        a1.z += __shfl_xor(a1.z, 32); a1.w += __shfl_xor(a1.w, 32);
        a2.x += __shfl_xor(a2.x, 32); a2.y += __shfl_xor(a2.y, 32);
        a2.z += __shfl_xor(a2.z, 32); a2.w += __shfl_xor(a2.w, 32);
        a3.x += __shfl_xor(a3.x, 32); a3.y += __shfl_xor(a3.y, 32);
        a3.z += __shfl_xor(a3.z, 32); a3.w += __shfl_xor(a3.w, 32);
        if (half == 0) {
            ((float4*)&xs[r * 512 + 0 * 128])[il] = a0;
            ((float4*)&xs[r * 512 + 1 * 128])[il] = a1;
            ((float4*)&xs[r * 512 + 2 * 128])[il] = a2;
            ((float4*)&xs[r * 512 + 3 * 128])[il] = a3;
        }
    }
    __syncthreads();
    float acc[RPB];
#pragma unroll
    for (int r = 0; r < RPB; ++r) acc[r] = 0.f;
    for (int k = 0; k < 128; k += 4) {
        float w0 = W1[(k + 0) * 256 + t];
        float w1 = W1[(k + 1) * 256 + t];
        float w2 = W1[(k + 2) * 256 + t];
        float w3 = W1[(k + 3) * 256 + t];
        int base = wv * 128 + k;
#pragma unroll
        for (int r = 0; r < RPB; ++r) {
            float4 xv = *(const float4*)&xs[r * 512 + base];
            acc[r] = fmaf(xv.x, w0, acc[r]);
            acc[r] = fmaf(xv.y, w1, acc[r]);
            acc[r] = fmaf(xv.z, w2, acc[r]);
            acc[r] = fmaf(xv.w, w3, acc[r]);
        }
    }
    float bv = b1[t];
#pragma unroll
    for (int r = 0; r < RPB; ++r) {
        float o = acc[r] + bv;
        o = o > 0.f ? o : (__expf(o) - 1.f);
        elu1[(size_t)(n0 + r) * 256 + t] = o;
    }
}

// ---------------- layer 2 ----------------
// gemm2 with fused el2/er2 computation
__global__ void k_gemm2(const float* __restrict__ xin, const float* __restrict__ W2T,
                        const float* __restrict__ al2, const float* __restrict__ ar2,
                        float* __restrict__ h2, float* __restrict__ el2,
                        float* __restrict__ er2) {
    __shared__ float xs[32 * 257];
    __shared__ float sel[8][32], ser[8][32];
    int t = threadIdx.x;
    int n0 = blockIdx.x * 32;
    for (int i = 0; i < 8; ++i) {
        int f = i * 256 + t;
        int row = f >> 6;
        int col = (f & 63) * 4;
        float4 v = make_float4(0.f, 0.f, 0.f, 0.f);
        if (n0 + row < NN) v = ((const float4*)xin)[(size_t)n0 * 64 + f];
        xs[row * 257 + col + 0] = v.x;
        xs[row * 257 + col + 1] = v.y;
        xs[row * 257 + col + 2] = v.z;
        xs[row * 257 + col + 3] = v.w;
    }
    __syncthreads();
    int nl = t & 31;
    int cg = t >> 5;
    int c0 = cg * 5;
    float acc[5] = {0, 0, 0, 0, 0};
    for (int k = 0; k < 256; k += 4) {
        float x0 = xs[nl * 257 + k + 0];
        float x1 = xs[nl * 257 + k + 1];
        float x2 = xs[nl * 257 + k + 2];
        float x3 = xs[nl * 257 + k + 3];
#pragma unroll
        for (int i = 0; i < 5; ++i) {
            float4 w = *(const float4*)&W2T[(c0 + i) * 256 + k];
            acc[i] = fmaf(x0, w.x, acc[i]);
            acc[i] = fmaf(x1, w.y, acc[i]);
            acc[i] = fmaf(x2, w.z, acc[i]);
            acc[i] = fmaf(x3, w.w, acc[i]);
        }
    }
    float pa = 0.f, pb = 0.f;
#pragma unroll
    for (int i = 0; i < 5; ++i) {
        pa = fmaf(acc[i], al2[c0 + i], pa);
        pb = fmaf(acc[i], ar2[c0 + i], pb);
    }
    sel[cg][nl] = pa;
    ser[cg][nl] = pb;
    int node = n0 + nl;
    if (node < NN) {
#pragma unroll
        for (int i = 0; i < 5; ++i) h2[(size_t)node * 40 + c0 + i] = acc[i];
    }
    __syncthreads();
    if (t < 32) {
        float s = 0.f;
#pragma unroll
        for (int g = 0; g < 8; ++g) s += sel[g][t];
        if (n0 + t < NN) el2[n0 + t] = s;
    } else if (t < 64) {
        int n2 = t - 32;
        float s = 0.f;
#pragma unroll
        for (int g = 0; g < 8; ++g) s += ser[g][n2];
        if (n0 + n2 < NN) er2[n0 + n2] = s;
    }
}

// wave-per-dst normalized weights (scalar head)
__global__ void k_w2n(const int* __restrict__ indptr, const int* __restrict__ srcs,
                      const float* __restrict__ el2, const float* __restrict__ er2,
                      float* __restrict__ w2s) {
    int t = threadIdx.x;
    int wv = t >> 6, l = t & 63;
    int d = blockIdx.x * 4 + wv;
    float rd = er2[d];
    int beg = indptr[d], end = indptr[d + 1];
    int j0 = beg + l;
    bool has = j0 < end;
    float wf = 0.f, sum = 0.f;
    if (has) {
        float e = el2[srcs[j0]] + rd;
        e = e > 0.f ? e : 0.2f * e;
        wf = __expf(e);
        sum = wf;
    }
    for (int j = j0 + 64; j < end; j += 64) {
        float e = el2[srcs[j]] + rd;
        e = e > 0.f ? e : 0.2f * e;
        float w = __expf(e);
        w2s[j] = w;
        sum += w;
    }
#pragma unroll
    for (int off = 32; off > 0; off >>= 1) sum += __shfl_xor(sum, off);
    float inv = sum > 0.f ? 1.f / sum : 0.f;
    if (has) w2s[j0] = wf * inv;
    for (int j = j0 + 64; j < end; j += 64) w2s[j] *= inv;
}

// final aggregation: wave per dst, 4-edge unroll with predication
__global__ void k_agg2b(const float* __restrict__ h2, const float* __restrict__ w2s,
                        const float* __restrict__ b2, const int* __restrict__ indptr,
                        const int* __restrict__ srcs, float* __restrict__ out) {
    int t = threadIdx.x;
    int wv = t >> 6, l = t & 63;
    int d = blockIdx.x * 4 + wv;
    int beg = indptr[d], end = indptr[d + 1];
    bool act = l < NCLS;
    float acc = 0.f;
    for (int j = beg; j < end; j += 4) {
        int j1 = j + 1, j2 = j + 2, j3 = j + 3;
        int s0 = srcs[j];
        int s1 = j1 < end ? srcs[j1] : s0;
        int s2 = j2 < end ? srcs[j2] : s0;
        int s3 = j3 < end ? srcs[j3] : s0;
        float w0 = w2s[j];
        float w1 = j1 < end ? w2s[j1] : 0.f;
        float w2 = j2 < end ? w2s[j2] : 0.f;
        float w3 = j3 < end ? w2s[j3] : 0.f;
        float v0 = act ? h2[(size_t)s0 * NCLS + l] : 0.f;
        float v1 = act ? h2[(size_t)s1 * NCLS + l] : 0.f;
        float v2 = act ? h2[(size_t)s2 * NCLS + l] : 0.f;
        float v3 = act ? h2[(size_t)s3 * NCLS + l] : 0.f;
        acc = fmaf(w0, v0, acc);
        acc = fmaf(w1, v1, acc);
        acc = fmaf(w2, v2, acc);
        acc = fmaf(w3, v3, acc);
    }
    if (act) out[(size_t)d * NCLS + l] = acc + b2[l];
}

extern "C" void kernel_launch(void* const* d_in, const int* in_sizes, int n_in,
                              void* d_out, int out_size, void* d_ws, size_t ws_size,
                              hipStream_t stream) {
    const float* x   = (const float*)d_in[0];
    const int*   src = (const int*)d_in[1];
    const int*   dst = (const int*)d_in[2];
    const float* W1  = (const float*)d_in[3];
    const float* al1 = (const float*)d_in[4];
    const float* ar1 = (const float*)d_in[5];
    const float* b1  = (const float*)d_in[6];
    const float* W2  = (const float*)d_in[7];
    const float* al2 = (const float*)d_in[8];
    const float* ar2 = (const float*)d_in[9];
    const float* b2  = (const float*)d_in[10];
    float* out = (float*)d_out;

    float* ws = (float*)d_ws;
    size_t off = 0;
    float* elu1 = ws + off; off += (size_t)NN * HID;
    float* h2   = ws + off; off += (size_t)NN * NCLS;
    float* el1  = ws + off; off += (size_t)NN * 4;
    float* er1  = ws + off; off += (size_t)NN * 4;
    float* el2  = ws + off; off += NN;
    float* er2  = ws + off; off += NN;
    float* wel  = ws + off; off += 512;
    float* wer  = ws + off; off += 512;
    float* w2t  = ws + off; off += (size_t)NCLS * 256;
    float* w4   = ws + off; off += (size_t)NE * 4;        // 16B-aligned
    float* w2s  = ws + off; off += NE;
    int* counts = (int*)(ws + off);
    int* indptr = counts + NN;
    int* fill   = indptr + NN + 1;
    int* srcs   = fill + NN;
    int* bsum   = srcs + NE;

    const int NB = (NN + 255) / 256;   // 196

    hipMemsetAsync(counts, 0, NN * sizeof(int), stream);

    k_count<<<(NE + 255) / 256, 256, 0, stream>>>(dst, counts);
    k_scanA<<<NB, 256, 0, stream>>>(counts, indptr, bsum);
    k_scanB<<<1, 256, 0, stream>>>(bsum, NB);
    k_scanC<<<NB, 256, 0, stream>>>(indptr, bsum, fill);
    k_scatter<<<(NE + 255) / 256, 256, 0, stream>>>(src, dst, indptr, fill, srcs);

    k_prep<<<1, 512, 0, stream>>>(W1, al1, ar1, W2, wel, wer, w2t);
    k_elr1x<<<(NN + 63) / 64, 256, 0, stream>>>(x, wel, wer, el1, er1);
    k_w1n<<<NN / 4, 256, 0, stream>>>(indptr, srcs, el1, er1, (float4*)w4);
    k_fused1<<<NN / RPB, 256, 0, stream>>>(x, W1, b1, indptr, srcs, (const float4*)w4, elu1);

    k_gemm2<<<(NN + 31) / 32, 256, 0, stream>>>(elu1, w2t, al2, ar2, h2, el2, er2);
    k_w2n<<<NN / 4, 256, 0, stream>>>(indptr, srcs, el2, er2, w2s);
    k_agg2b<<<NN / 4, 256, 0, stream>>>(h2, w2s, b2, indptr, srcs, out);
}

// Round 5
// 341.765 us; speedup vs baseline: 1.6980x; 1.1817x over previous
//
#include <hip/hip_runtime.h>

#define NN 50000
#define NE 800000
#define HID 256
#define NCLS 40

// ---------------- CSR build ----------------
__global__ void k_count(const int* __restrict__ dst, int* __restrict__ counts) {
    int e = blockIdx.x * 256 + threadIdx.x;
    if (e < NE) atomicAdd(&counts[dst[e]], 1);
}

__global__ void k_scanA(const int* __restrict__ counts, int* __restrict__ indptr,
                        int* __restrict__ bsum) {
    __shared__ int sh[256];
    int t = threadIdx.x;
    int idx = blockIdx.x * 256 + t;
    int c = idx < NN ? counts[idx] : 0;
    sh[t] = c;
    __syncthreads();
    for (int off = 1; off < 256; off <<= 1) {
        int v = (t >= off) ? sh[t - off] : 0;
        __syncthreads();
        sh[t] += v;
        __syncthreads();
    }
    if (idx < NN) indptr[idx] = sh[t] - c;
    if (t == 255) bsum[blockIdx.x] = sh[255];
}

__global__ void k_scanB(int* __restrict__ bsum, int nb) {
    __shared__ int sh[256];
    int t = threadIdx.x;
    int c = t < nb ? bsum[t] : 0;
    sh[t] = c;
    __syncthreads();
    for (int off = 1; off < 256; off <<= 1) {
        int v = (t >= off) ? sh[t - off] : 0;
        __syncthreads();
        sh[t] += v;
        __syncthreads();
    }
    if (t < nb) bsum[t] = sh[t] - c;
}

__global__ void k_scanC(int* __restrict__ indptr, const int* __restrict__ bsum,
                        int* __restrict__ fill) {
    int idx = blockIdx.x * 256 + threadIdx.x;
    if (idx < NN) {
        indptr[idx] += bsum[idx >> 8];
        fill[idx] = 0;
    }
    if (idx == 0) indptr[NN] = NE;
}

__global__ void k_scatter(const int* __restrict__ src, const int* __restrict__ dst,
                          const int* __restrict__ indptr, int* __restrict__ fill,
                          int* __restrict__ srcs) {
    int e = blockIdx.x * 256 + threadIdx.x;
    if (e < NE) {
        int d = dst[e];
        int pos = atomicAdd(&fill[d], 1);
        srcs[indptr[d] + pos] = src[e];
    }
}

// ---------------- tiny precompute ----------------
__global__ void k_prep(const float* __restrict__ W1, const float* __restrict__ al,
                       const float* __restrict__ ar, const float* __restrict__ W2,
                       float* __restrict__ wel, float* __restrict__ wer,
                       float* __restrict__ W2T) {
    int t = threadIdx.x;           // 512 threads
    int k = t >> 2, h = t & 3;
    float a = 0.f, b = 0.f;
    for (int dd = 0; dd < 64; ++dd) {
        float w = W1[k * 256 + h * 64 + dd];
        a = fmaf(w, al[h * 64 + dd], a);
        b = fmaf(w, ar[h * 64 + dd], b);
    }
    wel[k * 4 + h] = a;
    wer[k * 4 + h] = b;
    for (int i = t; i < 256 * NCLS; i += 512) {
        int c = i >> 8, kk = i & 255;
        W2T[i] = W2[kk * 40 + c];
    }
}

// el1/er1[N,4] = x @ wel / x @ wer ; 64 nodes per block
__global__ void k_elr1x(const float* __restrict__ x, const float* __restrict__ wel,
                        const float* __restrict__ wer, float* __restrict__ el1,
                        float* __restrict__ er1) {
    __shared__ float xs[64 * 129];
    __shared__ float wels[512], wers[512];
    int t = threadIdx.x;
    int n0 = blockIdx.x * 64;
    wels[t] = wel[t]; wels[256 + t] = wel[256 + t];
    wers[t] = wer[t]; wers[256 + t] = wer[256 + t];
    for (int i = 0; i < 8; ++i) {
        int f = i * 256 + t;
        int row = f >> 5;
        int col4 = (f & 31) * 4;
        float4 v = make_float4(0.f, 0.f, 0.f, 0.f);
        if (n0 + row < NN) v = ((const float4*)x)[(size_t)n0 * 32 + f];
        xs[row * 129 + col4 + 0] = v.x;
        xs[row * 129 + col4 + 1] = v.y;
        xs[row * 129 + col4 + 2] = v.z;
        xs[row * 129 + col4 + 3] = v.w;
    }
    __syncthreads();
    int node = t & 63;
    int h = t >> 6;
    float a = 0.f, b = 0.f;
    for (int k = 0; k < 128; ++k) {
        float xv = xs[node * 129 + k];
        a = fmaf(xv, wels[k * 4 + h], a);
        b = fmaf(xv, wers[k * 4 + h], b);
    }
    if (n0 + node < NN) {
        el1[(size_t)(n0 + node) * 4 + h] = a;
        er1[(size_t)(n0 + node) * 4 + h] = b;
    }
}

// fused layer-1: in-register softmax weights + deep-MLP x-gather -> LDS -> @W1+bias+ELU
#define RPB 8
__global__ void k_fused1(const float* __restrict__ x, const float* __restrict__ W1,
                         const float* __restrict__ b1, const float* __restrict__ el1,
                         const float* __restrict__ er1, const int* __restrict__ indptr,
                         const int* __restrict__ srcs, float* __restrict__ elu1) {
    __shared__ float xs[RPB * 512];        // 16 KB
    __shared__ int   si[4][64];            // 1 KB
    __shared__ float4 sw[4][64];           // 4 KB
    int t = threadIdx.x;
    int wv = t >> 6, l = t & 63;
    int n0 = blockIdx.x * RPB;
    for (int rr = 0; rr < 2; ++rr) {
        int r = rr * 4 + wv;
        int d = n0 + r;
        int beg = indptr[d], end = indptr[d + 1];
        int deg = end - beg;
        float4 rd = *(const float4*)&er1[(size_t)d * 4];
        // ---- pass 1: weights (lane-parallel over edges) ----
        int s_l = 0;
        float4 w = make_float4(0.f, 0.f, 0.f, 0.f);
        if (l < deg) {
            s_l = srcs[beg + l];
            float4 ls = *(const float4*)&el1[(size_t)s_l * 4];
            float e0 = ls.x + rd.x, e1 = ls.y + rd.y, e2 = ls.z + rd.z, e3 = ls.w + rd.w;
            e0 = e0 > 0.f ? e0 : 0.2f * e0;
            e1 = e1 > 0.f ? e1 : 0.2f * e1;
            e2 = e2 > 0.f ? e2 : 0.2f * e2;
            e3 = e3 > 0.f ? e3 : 0.2f * e3;
            w = make_float4(__expf(e0), __expf(e1), __expf(e2), __expf(e3));
        }
        float s0 = w.x, s1 = w.y, s2 = w.z, s3 = w.w;
        for (int j = beg + 64 + l; j < end; j += 64) {     // deg>64 (rare)
            float4 ls = *(const float4*)&el1[(size_t)srcs[j] * 4];
            float e0 = ls.x + rd.x, e1 = ls.y + rd.y, e2 = ls.z + rd.z, e3 = ls.w + rd.w;
            e0 = e0 > 0.f ? e0 : 0.2f * e0;
            e1 = e1 > 0.f ? e1 : 0.2f * e1;
            e2 = e2 > 0.f ? e2 : 0.2f * e2;
            e3 = e3 > 0.f ? e3 : 0.2f * e3;
            s0 += __expf(e0); s1 += __expf(e1); s2 += __expf(e2); s3 += __expf(e3);
        }
#pragma unroll
        for (int off = 32; off > 0; off >>= 1) {
            s0 += __shfl_xor(s0, off);
            s1 += __shfl_xor(s1, off);
            s2 += __shfl_xor(s2, off);
            s3 += __shfl_xor(s3, off);
        }
        float i0 = s0 > 0.f ? 1.f / s0 : 0.f;
        float i1 = s1 > 0.f ? 1.f / s1 : 0.f;
        float i2 = s2 > 0.f ? 1.f / s2 : 0.f;
        float i3 = s3 > 0.f ? 1.f / s3 : 0.f;
        si[wv][l] = s_l;                                   // 0 for l>=deg
        sw[wv][l] = make_float4(w.x * i0, w.y * i1, w.z * i2, w.w * i3);
        // ---- pass 2: x-gather, 4 independent rows in flight ----
        float2 a0 = {0.f, 0.f}, a1 = {0.f, 0.f}, a2 = {0.f, 0.f}, a3 = {0.f, 0.f};
        int dege = deg < 64 ? deg : 64;
        for (int e = 0; e < dege; e += 4) {
            int ix0 = si[wv][e + 0];
            int ix1 = si[wv][e + 1];
            int ix2 = si[wv][e + 2];
            int ix3 = si[wv][e + 3];
            float4 w0 = sw[wv][e + 0];
            float4 w1 = sw[wv][e + 1];
            float4 w2 = sw[wv][e + 2];
            float4 w3 = sw[wv][e + 3];
            float2 x0 = *(const float2*)&x[(size_t)ix0 * 128 + 2 * l];
            float2 x1 = *(const float2*)&x[(size_t)ix1 * 128 + 2 * l];
            float2 x2 = *(const float2*)&x[(size_t)ix2 * 128 + 2 * l];
            float2 x3 = *(const float2*)&x[(size_t)ix3 * 128 + 2 * l];
            a0.x = fmaf(w0.x, x0.x, a0.x); a0.y = fmaf(w0.x, x0.y, a0.y);
            a1.x = fmaf(w0.y, x0.x, a1.x); a1.y = fmaf(w0.y, x0.y, a1.y);
            a2.x = fmaf(w0.z, x0.x, a2.x); a2.y = fmaf(w0.z, x0.y, a2.y);
            a3.x = fmaf(w0.w, x0.x, a3.x); a3.y = fmaf(w0.w, x0.y, a3.y);
            a0.x = fmaf(w1.x, x1.x, a0.x); a0.y = fmaf(w1.x, x1.y, a0.y);
            a1.x = fmaf(w1.y, x1.x, a1.x); a1.y = fmaf(w1.y, x1.y, a1.y);
            a2.x = fmaf(w1.z, x1.x, a2.x); a2.y = fmaf(w1.z, x1.y, a2.y);
            a3.x = fmaf(w1.w, x1.x, a3.x); a3.y = fmaf(w1.w, x1.y, a3.y);
            a0.x = fmaf(w2.x, x2.x, a0.x); a0.y = fmaf(w2.x, x2.y, a0.y);
            a1.x = fmaf(w2.y, x2.x, a1.x); a1.y = fmaf(w2.y, x2.y, a1.y);
            a2.x = fmaf(w2.z, x2.x, a2.x); a2.y = fmaf(w2.z, x2.y, a2.y);
            a3.x = fmaf(w2.w, x2.x, a3.x); a3.y = fmaf(w2.w, x2.y, a3.y);
            a0.x = fmaf(w3.x, x3.x, a0.x); a0.y = fmaf(w3.x, x3.y, a0.y);
            a1.x = fmaf(w3.y, x3.x, a1.x); a1.y = fmaf(w3.y, x3.y, a1.y);
            a2.x = fmaf(w3.z, x3.x, a2.x); a2.y = fmaf(w3.z, x3.y, a2.y);
            a3.x = fmaf(w3.w, x3.x, a3.x); a3.y = fmaf(w3.w, x3.y, a3.y);
        }
        for (int j = beg + 64; j < end; ++j) {             // deg>64 (rare)
            int s = srcs[j];
            float4 ls = *(const float4*)&el1[(size_t)s * 4];
            float e0 = ls.x + rd.x, e1 = ls.y + rd.y, e2 = ls.z + rd.z, e3 = ls.w + rd.w;
            e0 = e0 > 0.f ? e0 : 0.2f * e0;
            e1 = e1 > 0.f ? e1 : 0.2f * e1;
            e2 = e2 > 0.f ? e2 : 0.2f * e2;
            e3 = e3 > 0.f ? e3 : 0.2f * e3;
            float w0 = __expf(e0) * i0, w1 = __expf(e1) * i1;
            float w2 = __expf(e2) * i2, w3 = __expf(e3) * i3;
            float2 xv = *(const float2*)&x[(size_t)s * 128 + 2 * l];
            a0.x = fmaf(w0, xv.x, a0.x); a0.y = fmaf(w0, xv.y, a0.y);
            a1.x = fmaf(w1, xv.x, a1.x); a1.y = fmaf(w1, xv.y, a1.y);
            a2.x = fmaf(w2, xv.x, a2.x); a2.y = fmaf(w2, xv.y, a2.y);
            a3.x = fmaf(w3, xv.x, a3.x); a3.y = fmaf(w3, xv.y, a3.y);
        }
        *(float2*)&xs[r * 512 + 0 * 128 + 2 * l] = a0;
        *(float2*)&xs[r * 512 + 1 * 128 + 2 * l] = a1;
        *(float2*)&xs[r * 512 + 2 * 128 + 2 * l] = a2;
        *(float2*)&xs[r * 512 + 3 * 128 + 2 * l] = a3;
    }
    __syncthreads();
    // ---- GEMM phase: thread t = output column, wv = head ----
    float acc[RPB];
#pragma unroll
    for (int r = 0; r < RPB; ++r) acc[r] = 0.f;
    for (int k = 0; k < 128; k += 4) {
        float w0 = W1[(k + 0) * 256 + t];
        float w1 = W1[(k + 1) * 256 + t];
        float w2 = W1[(k + 2) * 256 + t];
        float w3 = W1[(k + 3) * 256 + t];
        int base = wv * 128 + k;
#pragma unroll
        for (int r = 0; r < RPB; ++r) {
            float4 xv = *(const float4*)&xs[r * 512 + base];
            acc[r] = fmaf(xv.x, w0, acc[r]);
            acc[r] = fmaf(xv.y, w1, acc[r]);
            acc[r] = fmaf(xv.z, w2, acc[r]);
            acc[r] = fmaf(xv.w, w3, acc[r]);
        }
    }
    float bv = b1[t];
#pragma unroll
    for (int r = 0; r < RPB; ++r) {
        float o = acc[r] + bv;
        o = o > 0.f ? o : (__expf(o) - 1.f);
        elu1[(size_t)(n0 + r) * 256 + t] = o;
    }
}

// ---------------- layer 2 ----------------
__global__ void k_gemm2(const float* __restrict__ xin, const float* __restrict__ W2T,
                        const float* __restrict__ al2, const float* __restrict__ ar2,
                        float* __restrict__ h2, float* __restrict__ el2,
                        float* __restrict__ er2) {
    __shared__ float xs[32 * 257];
    __shared__ float sel[8][32], ser[8][32];
    int t = threadIdx.x;
    int n0 = blockIdx.x * 32;
    for (int i = 0; i < 8; ++i) {
        int f = i * 256 + t;
        int row = f >> 6;
        int col = (f & 63) * 4;
        float4 v = make_float4(0.f, 0.f, 0.f, 0.f);
        if (n0 + row < NN) v = ((const float4*)xin)[(size_t)n0 * 64 + f];
        xs[row * 257 + col + 0] = v.x;
        xs[row * 257 + col + 1] = v.y;
        xs[row * 257 + col + 2] = v.z;
        xs[row * 257 + col + 3] = v.w;
    }
    __syncthreads();
    int nl = t & 31;
    int cg = t >> 5;
    int c0 = cg * 5;
    float acc[5] = {0, 0, 0, 0, 0};
    for (int k = 0; k < 256; k += 4) {
        float x0 = xs[nl * 257 + k + 0];
        float x1 = xs[nl * 257 + k + 1];
        float x2 = xs[nl * 257 + k + 2];
        float x3 = xs[nl * 257 + k + 3];
#pragma unroll
        for (int i = 0; i < 5; ++i) {
            float4 w = *(const float4*)&W2T[(c0 + i) * 256 + k];
            acc[i] = fmaf(x0, w.x, acc[i]);
            acc[i] = fmaf(x1, w.y, acc[i]);
            acc[i] = fmaf(x2, w.z, acc[i]);
            acc[i] = fmaf(x3, w.w, acc[i]);
        }
    }
    float pa = 0.f, pb = 0.f;
#pragma unroll
    for (int i = 0; i < 5; ++i) {
        pa = fmaf(acc[i], al2[c0 + i], pa);
        pb = fmaf(acc[i], ar2[c0 + i], pb);
    }
    sel[cg][nl] = pa;
    ser[cg][nl] = pb;
    int node = n0 + nl;
    if (node < NN) {
#pragma unroll
        for (int i = 0; i < 5; ++i) h2[(size_t)node * 40 + c0 + i] = acc[i];
    }
    __syncthreads();
    if (t < 32) {
        float s = 0.f;
#pragma unroll
        for (int g = 0; g < 8; ++g) s += sel[g][t];
        if (n0 + t < NN) el2[n0 + t] = s;
    } else if (t < 64) {
        int n2 = t - 32;
        float s = 0.f;
#pragma unroll
        for (int g = 0; g < 8; ++g) s += ser[g][n2];
        if (n0 + n2 < NN) er2[n0 + n2] = s;
    }
}

// merged layer-2 softmax + aggregation: wave per dst
__global__ void k_agg2(const float* __restrict__ h2, const float* __restrict__ el2,
                       const float* __restrict__ er2, const float* __restrict__ b2,
                       const int* __restrict__ indptr, const int* __restrict__ srcs,
                       float* __restrict__ out) {
    __shared__ int   si[4][64];
    __shared__ float sw[4][64];
    int t = threadIdx.x;
    int wv = t >> 6, l = t & 63;
    int d = blockIdx.x * 4 + wv;
    int beg = indptr[d], end = indptr[d + 1];
    int deg = end - beg;
    float rd = er2[d];
    int s_l = 0;
    float w = 0.f;
    if (l < deg) {
        s_l = srcs[beg + l];
        float e = el2[s_l] + rd;
        e = e > 0.f ? e : 0.2f * e;
        w = __expf(e);
    }
    float sum = w;
    for (int j = beg + 64 + l; j < end; j += 64) {
        float e = el2[srcs[j]] + rd;
        e = e > 0.f ? e : 0.2f * e;
        sum += __expf(e);
    }
#pragma unroll
    for (int off = 32; off > 0; off >>= 1) sum += __shfl_xor(sum, off);
    float inv = sum > 0.f ? 1.f / sum : 0.f;
    si[wv][l] = s_l;
    sw[wv][l] = w * inv;
    float acc = 0.f;
    bool act = l < NCLS;
    int dege = deg < 64 ? deg : 64;
    for (int e = 0; e < dege; e += 4) {
        int ix0 = si[wv][e + 0];
        int ix1 = si[wv][e + 1];
        int ix2 = si[wv][e + 2];
        int ix3 = si[wv][e + 3];
        float w0 = sw[wv][e + 0];
        float w1 = sw[wv][e + 1];
        float w2 = sw[wv][e + 2];
        float w3 = sw[wv][e + 3];
        float v0 = act ? h2[(size_t)ix0 * NCLS + l] : 0.f;
        float v1 = act ? h2[(size_t)ix1 * NCLS + l] : 0.f;
        float v2 = act ? h2[(size_t)ix2 * NCLS + l] : 0.f;
        float v3 = act ? h2[(size_t)ix3 * NCLS + l] : 0.f;
        acc = fmaf(w0, v0, acc);
        acc = fmaf(w1, v1, acc);
        acc = fmaf(w2, v2, acc);
        acc = fmaf(w3, v3, acc);
    }
    for (int j = beg + 64; j < end; ++j) {     // deg>64 (rare)
        int s = srcs[j];
        float e = el2[s] + rd;
        e = e > 0.f ? e : 0.2f * e;
        float ww = __expf(e) * inv;
        float v = act ? h2[(size_t)s * NCLS + l] : 0.f;
        acc = fmaf(ww, v, acc);
    }
    if (act) out[(size_t)d * NCLS + l] = acc + b2[l];
}

extern "C" void kernel_launch(void* const* d_in, const int* in_sizes, int n_in,
                              void* d_out, int out_size, void* d_ws, size_t ws_size,
                              hipStream_t stream) {
    const float* x   = (const float*)d_in[0];
    const int*   src = (const int*)d_in[1];
    const int*   dst = (const int*)d_in[2];
    const float* W1  = (const float*)d_in[3];
    const float* al1 = (const float*)d_in[4];
    const float* ar1 = (const float*)d_in[5];
    const float* b1  = (const float*)d_in[6];
    const float* W2  = (const float*)d_in[7];
    const float* al2 = (const float*)d_in[8];
    const float* ar2 = (const float*)d_in[9];
    const float* b2  = (const float*)d_in[10];
    float* out = (float*)d_out;

    float* ws = (float*)d_ws;
    size_t off = 0;
    float* elu1 = ws + off; off += (size_t)NN * HID;
    float* h2   = ws + off; off += (size_t)NN * NCLS;
    float* el1  = ws + off; off += (size_t)NN * 4;
    float* er1  = ws + off; off += (size_t)NN * 4;
    float* el2  = ws + off; off += NN;
    float* er2  = ws + off; off += NN;
    float* wel  = ws + off; off += 512;
    float* wer  = ws + off; off += 512;
    float* w2t  = ws + off; off += (size_t)NCLS * 256;
    int* counts = (int*)(ws + off);
    int* indptr = counts + NN;
    int* fill   = indptr + NN + 1;
    int* srcs   = fill + NN;
    int* bsum   = srcs + NE;

    const int NB = (NN + 255) / 256;

    hipMemsetAsync(counts, 0, NN * sizeof(int), stream);

    k_count<<<(NE + 255) / 256, 256, 0, stream>>>(dst, counts);
    k_scanA<<<NB, 256, 0, stream>>>(counts, indptr, bsum);
    k_scanB<<<1, 256, 0, stream>>>(bsum, NB);
    k_scanC<<<NB, 256, 0, stream>>>(indptr, bsum, fill);
    k_scatter<<<(NE + 255) / 256, 256, 0, stream>>>(src, dst, indptr, fill, srcs);

    k_prep<<<1, 512, 0, stream>>>(W1, al1, ar1, W2, wel, wer, w2t);
    k_elr1x<<<(NN + 63) / 64, 256, 0, stream>>>(x, wel, wer, el1, er1);
    k_fused1<<<NN / RPB, 256, 0, stream>>>(x, W1, b1, el1, er1, indptr, srcs, elu1);

    k_gemm2<<<(NN + 31) / 32, 256, 0, stream>>>(elu1, w2t, al2, ar2, h2, el2, er2);
    k_agg2<<<NN / 4, 256, 0, stream>>>(h2, el2, er2, b2, indptr, srcs, out);
}

// Round 6
// 330.961 us; speedup vs baseline: 1.7534x; 1.0326x over previous
//
#include <hip/hip_runtime.h>

#define NN 50000
#define NE 800000
#define HID 256
#define NCLS 40

__device__ inline unsigned short f2bf(float f) {            // RNE float->bf16
    unsigned int u = __float_as_uint(f);
    unsigned int r = (u + 0x7FFFu + ((u >> 16) & 1u)) >> 16;
    return (unsigned short)r;
}
__device__ inline float2 bf2x(unsigned int u) {             // 2 bf16 -> 2 f32
    return make_float2(__uint_as_float(u << 16), __uint_as_float(u & 0xFFFF0000u));
}

// ---------------- CSR build ----------------
__global__ void k_count(const int* __restrict__ dst, int* __restrict__ counts) {
    int e = blockIdx.x * 256 + threadIdx.x;
    if (e < NE) atomicAdd(&counts[dst[e]], 1);
}

__global__ void k_scanA(const int* __restrict__ counts, int* __restrict__ indptr,
                        int* __restrict__ bsum) {
    __shared__ int sh[256];
    int t = threadIdx.x;
    int idx = blockIdx.x * 256 + t;
    int c = idx < NN ? counts[idx] : 0;
    sh[t] = c;
    __syncthreads();
    for (int off = 1; off < 256; off <<= 1) {
        int v = (t >= off) ? sh[t - off] : 0;
        __syncthreads();
        sh[t] += v;
        __syncthreads();
    }
    if (idx < NN) indptr[idx] = sh[t] - c;
    if (t == 255) bsum[blockIdx.x] = sh[255];
}

__global__ void k_scanB(int* __restrict__ bsum, int nb) {
    __shared__ int sh[256];
    int t = threadIdx.x;
    int c = t < nb ? bsum[t] : 0;
    sh[t] = c;
    __syncthreads();
    for (int off = 1; off < 256; off <<= 1) {
        int v = (t >= off) ? sh[t - off] : 0;
        __syncthreads();
        sh[t] += v;
        __syncthreads();
    }
    if (t < nb) bsum[t] = sh[t] - c;
}

__global__ void k_scanC(int* __restrict__ indptr, const int* __restrict__ bsum,
                        int* __restrict__ fill) {
    int idx = blockIdx.x * 256 + threadIdx.x;
    if (idx < NN) {
        indptr[idx] += bsum[idx >> 8];
        fill[idx] = 0;
    }
    if (idx == 0) indptr[NN] = NE;
}

__global__ void k_scatter(const int* __restrict__ src, const int* __restrict__ dst,
                          const int* __restrict__ indptr, int* __restrict__ fill,
                          int* __restrict__ srcs) {
    int e = blockIdx.x * 256 + threadIdx.x;
    if (e < NE) {
        int d = dst[e];
        int pos = atomicAdd(&fill[d], 1);
        srcs[indptr[d] + pos] = src[e];
    }
}

// ---------------- tiny precompute ----------------
__global__ void k_prep(const float* __restrict__ W1, const float* __restrict__ al,
                       const float* __restrict__ ar, const float* __restrict__ W2,
                       float* __restrict__ wel, float* __restrict__ wer,
                       float* __restrict__ W2T) {
    int t = threadIdx.x;           // 512 threads
    int k = t >> 2, h = t & 3;
    float a = 0.f, b = 0.f;
    for (int dd = 0; dd < 64; ++dd) {
        float w = W1[k * 256 + h * 64 + dd];
        a = fmaf(w, al[h * 64 + dd], a);
        b = fmaf(w, ar[h * 64 + dd], b);
    }
    wel[k * 4 + h] = a;
    wer[k * 4 + h] = b;
    for (int i = t; i < 256 * NCLS; i += 512) {
        int c = i >> 8, kk = i & 255;
        W2T[i] = W2[kk * 40 + c];
    }
}

// el1/er1[N,4] = x @ wel / x @ wer ; also emit bf16 copy of x
__global__ void k_elr1x(const float* __restrict__ x, const float* __restrict__ wel,
                        const float* __restrict__ wer, float* __restrict__ el1,
                        float* __restrict__ er1, unsigned short* __restrict__ xb) {
    __shared__ float xs[64 * 129];
    __shared__ float wels[512], wers[512];
    int t = threadIdx.x;
    int n0 = blockIdx.x * 64;
    wels[t] = wel[t]; wels[256 + t] = wel[256 + t];
    wers[t] = wer[t]; wers[256 + t] = wer[256 + t];
    for (int i = 0; i < 8; ++i) {
        int f = i * 256 + t;
        int row = f >> 5;
        int col4 = (f & 31) * 4;
        float4 v = make_float4(0.f, 0.f, 0.f, 0.f);
        if (n0 + row < NN) v = ((const float4*)x)[(size_t)n0 * 32 + f];
        xs[row * 129 + col4 + 0] = v.x;
        xs[row * 129 + col4 + 1] = v.y;
        xs[row * 129 + col4 + 2] = v.z;
        xs[row * 129 + col4 + 3] = v.w;
    }
    __syncthreads();
    int node = t & 63;
    int h = t >> 6;
    float a = 0.f, b = 0.f;
    for (int k = 0; k < 128; ++k) {
        float xv = xs[node * 129 + k];
        a = fmaf(xv, wels[k * 4 + h], a);
        b = fmaf(xv, wers[k * 4 + h], b);
    }
    if (n0 + node < NN) {
        el1[(size_t)(n0 + node) * 4 + h] = a;
        er1[(size_t)(n0 + node) * 4 + h] = b;
    }
    // bf16 copy: 64 rows x 128 cols = 8192 elems; 4 x ushort8 per thread
    for (int i = 0; i < 4; ++i) {
        int g = (i * 256 + t) * 8;          // first elem
        int row = g >> 7, col = g & 127;
        if (n0 + row < NN) {
            ushort4 lo, hi;
            lo.x = f2bf(xs[row * 129 + col + 0]);
            lo.y = f2bf(xs[row * 129 + col + 1]);
            lo.z = f2bf(xs[row * 129 + col + 2]);
            lo.w = f2bf(xs[row * 129 + col + 3]);
            hi.x = f2bf(xs[row * 129 + col + 4]);
            hi.y = f2bf(xs[row * 129 + col + 5]);
            hi.z = f2bf(xs[row * 129 + col + 6]);
            hi.w = f2bf(xs[row * 129 + col + 7]);
            *(ushort4*)&xb[(size_t)(n0 + row) * 128 + col] = lo;
            *(ushort4*)&xb[(size_t)(n0 + row) * 128 + col + 4] = hi;
        }
    }
}

// fused layer-1: in-register softmax + deep-MLP bf16 x-gather -> LDS -> @W1+bias+ELU(bf16)
#define RPB 8
__global__ void k_fused1(const unsigned int* __restrict__ xb32,
                         const float* __restrict__ W1,
                         const float* __restrict__ b1, const float* __restrict__ el1,
                         const float* __restrict__ er1, const int* __restrict__ indptr,
                         const int* __restrict__ srcs,
                         unsigned short* __restrict__ elu1) {
    __shared__ float xs[RPB * 512];        // 16 KB
    __shared__ int   si[4][64];            // 1 KB
    __shared__ float4 sw[4][64];           // 4 KB
    int t = threadIdx.x;
    int wv = t >> 6, l = t & 63;
    int n0 = blockIdx.x * RPB;
    for (int rr = 0; rr < 2; ++rr) {
        int r = rr * 4 + wv;
        int d = n0 + r;
        int beg = indptr[d], end = indptr[d + 1];
        int deg = end - beg;
        float4 rd = *(const float4*)&er1[(size_t)d * 4];
        // ---- pass 1: weights (lane-parallel over edges) ----
        int s_l = 0;
        float4 w = make_float4(0.f, 0.f, 0.f, 0.f);
        if (l < deg) {
            s_l = srcs[beg + l];
            float4 ls = *(const float4*)&el1[(size_t)s_l * 4];
            float e0 = ls.x + rd.x, e1 = ls.y + rd.y, e2 = ls.z + rd.z, e3 = ls.w + rd.w;
            e0 = e0 > 0.f ? e0 : 0.2f * e0;
            e1 = e1 > 0.f ? e1 : 0.2f * e1;
            e2 = e2 > 0.f ? e2 : 0.2f * e2;
            e3 = e3 > 0.f ? e3 : 0.2f * e3;
            w = make_float4(__expf(e0), __expf(e1), __expf(e2), __expf(e3));
        }
        float s0 = w.x, s1 = w.y, s2 = w.z, s3 = w.w;
        for (int j = beg + 64 + l; j < end; j += 64) {     // deg>64 (rare)
            float4 ls = *(const float4*)&el1[(size_t)srcs[j] * 4];
            float e0 = ls.x + rd.x, e1 = ls.y + rd.y, e2 = ls.z + rd.z, e3 = ls.w + rd.w;
            e0 = e0 > 0.f ? e0 : 0.2f * e0;
            e1 = e1 > 0.f ? e1 : 0.2f * e1;
            e2 = e2 > 0.f ? e2 : 0.2f * e2;
            e3 = e3 > 0.f ? e3 : 0.2f * e3;
            s0 += __expf(e0); s1 += __expf(e1); s2 += __expf(e2); s3 += __expf(e3);
        }
#pragma unroll
        for (int off = 32; off > 0; off >>= 1) {
            s0 += __shfl_xor(s0, off);
            s1 += __shfl_xor(s1, off);
            s2 += __shfl_xor(s2, off);
            s3 += __shfl_xor(s3, off);
        }
        float i0 = s0 > 0.f ? 1.f / s0 : 0.f;
        float i1 = s1 > 0.f ? 1.f / s1 : 0.f;
        float i2 = s2 > 0.f ? 1.f / s2 : 0.f;
        float i3 = s3 > 0.f ? 1.f / s3 : 0.f;
        si[wv][l] = s_l;
        sw[wv][l] = make_float4(w.x * i0, w.y * i1, w.z * i2, w.w * i3);
        // ---- pass 2: bf16 x-gather, 4 independent rows in flight ----
        float2 a0 = {0.f, 0.f}, a1 = {0.f, 0.f}, a2 = {0.f, 0.f}, a3 = {0.f, 0.f};
        int dege = deg < 64 ? deg : 64;
        for (int e = 0; e < dege; e += 4) {
            int ix0 = si[wv][e + 0];
            int ix1 = si[wv][e + 1];
            int ix2 = si[wv][e + 2];
            int ix3 = si[wv][e + 3];
            float4 w0 = sw[wv][e + 0];
            float4 w1 = sw[wv][e + 1];
            float4 w2 = sw[wv][e + 2];
            float4 w3 = sw[wv][e + 3];
            unsigned int u0 = xb32[(size_t)ix0 * 64 + l];
            unsigned int u1 = xb32[(size_t)ix1 * 64 + l];
            unsigned int u2 = xb32[(size_t)ix2 * 64 + l];
            unsigned int u3 = xb32[(size_t)ix3 * 64 + l];
            float2 x0 = bf2x(u0);
            float2 x1 = bf2x(u1);
            float2 x2 = bf2x(u2);
            float2 x3 = bf2x(u3);
            a0.x = fmaf(w0.x, x0.x, a0.x); a0.y = fmaf(w0.x, x0.y, a0.y);
            a1.x = fmaf(w0.y, x0.x, a1.x); a1.y = fmaf(w0.y, x0.y, a1.y);
            a2.x = fmaf(w0.z, x0.x, a2.x); a2.y = fmaf(w0.z, x0.y, a2.y);
            a3.x = fmaf(w0.w, x0.x, a3.x); a3.y = fmaf(w0.w, x0.y, a3.y);
            a0.x = fmaf(w1.x, x1.x, a0.x); a0.y = fmaf(w1.x, x1.y, a0.y);
            a1.x = fmaf(w1.y, x1.x, a1.x); a1.y = fmaf(w1.y, x1.y, a1.y);
            a2.x = fmaf(w1.z, x1.x, a2.x); a2.y = fmaf(w1.z, x1.y, a2.y);
            a3.x = fmaf(w1.w, x1.x, a3.x); a3.y = fmaf(w1.w, x1.y, a3.y);
            a0.x = fmaf(w2.x, x2.x, a0.x); a0.y = fmaf(w2.x, x2.y, a0.y);
            a1.x = fmaf(w2.y, x2.x, a1.x); a1.y = fmaf(w2.y, x2.y, a1.y);
            a2.x = fmaf(w2.z, x2.x, a2.x); a2.y = fmaf(w2.z, x2.y, a2.y);
            a3.x = fmaf(w2.w, x2.x, a3.x); a3.y = fmaf(w2.w, x2.y, a3.y);
            a0.x = fmaf(w3.x, x3.x, a0.x); a0.y = fmaf(w3.x, x3.y, a0.y);
            a1.x = fmaf(w3.y, x3.x, a1.x); a1.y = fmaf(w3.y, x3.y, a1.y);
            a2.x = fmaf(w3.z, x3.x, a2.x); a2.y = fmaf(w3.z, x3.y, a2.y);
            a3.x = fmaf(w3.w, x3.x, a3.x); a3.y = fmaf(w3.w, x3.y, a3.y);
        }
        for (int j = beg + 64; j < end; ++j) {             // deg>64 (rare)
            int s = srcs[j];
            float4 ls = *(const float4*)&el1[(size_t)s * 4];
            float e0 = ls.x + rd.x, e1 = ls.y + rd.y, e2 = ls.z + rd.z, e3 = ls.w + rd.w;
            e0 = e0 > 0.f ? e0 : 0.2f * e0;
            e1 = e1 > 0.f ? e1 : 0.2f * e1;
            e2 = e2 > 0.f ? e2 : 0.2f * e2;
            e3 = e3 > 0.f ? e3 : 0.2f * e3;
            float w0 = __expf(e0) * i0, w1 = __expf(e1) * i1;
            float w2 = __expf(e2) * i2, w3 = __expf(e3) * i3;
            float2 xv = bf2x(xb32[(size_t)s * 64 + l]);
            a0.x = fmaf(w0, xv.x, a0.x); a0.y = fmaf(w0, xv.y, a0.y);
            a1.x = fmaf(w1, xv.x, a1.x); a1.y = fmaf(w1, xv.y, a1.y);
            a2.x = fmaf(w2, xv.x, a2.x); a2.y = fmaf(w2, xv.y, a2.y);
            a3.x = fmaf(w3, xv.x, a3.x); a3.y = fmaf(w3, xv.y, a3.y);
        }
        *(float2*)&xs[r * 512 + 0 * 128 + 2 * l] = a0;
        *(float2*)&xs[r * 512 + 1 * 128 + 2 * l] = a1;
        *(float2*)&xs[r * 512 + 2 * 128 + 2 * l] = a2;
        *(float2*)&xs[r * 512 + 3 * 128 + 2 * l] = a3;
    }
    __syncthreads();
    // ---- GEMM phase: thread t = output column, wv = head ----
    float acc[RPB];
#pragma unroll
    for (int r = 0; r < RPB; ++r) acc[r] = 0.f;
    for (int k = 0; k < 128; k += 4) {
        float w0 = W1[(k + 0) * 256 + t];
        float w1 = W1[(k + 1) * 256 + t];
        float w2 = W1[(k + 2) * 256 + t];
        float w3 = W1[(k + 3) * 256 + t];
        int base = wv * 128 + k;
#pragma unroll
        for (int r = 0; r < RPB; ++r) {
            float4 xv = *(const float4*)&xs[r * 512 + base];
            acc[r] = fmaf(xv.x, w0, acc[r]);
            acc[r] = fmaf(xv.y, w1, acc[r]);
            acc[r] = fmaf(xv.z, w2, acc[r]);
            acc[r] = fmaf(xv.w, w3, acc[r]);
        }
    }
    float bv = b1[t];
#pragma unroll
    for (int r = 0; r < RPB; ++r) {
        float o = acc[r] + bv;
        o = o > 0.f ? o : (__expf(o) - 1.f);
        elu1[(size_t)(n0 + r) * 256 + t] = f2bf(o);
    }
}

// ---------------- layer 2 ----------------
// gemm2 on bf16 input with fused el2/er2
__global__ void k_gemm2(const unsigned int* __restrict__ xin32,
                        const float* __restrict__ W2T,
                        const float* __restrict__ al2, const float* __restrict__ ar2,
                        float* __restrict__ h2, float* __restrict__ el2,
                        float* __restrict__ er2) {
    __shared__ float xs[32 * 257];
    __shared__ float sel[8][32], ser[8][32];
    int t = threadIdx.x;
    int n0 = blockIdx.x * 32;
    // stage 32 rows x 256 bf16 cols -> fp32 LDS; uint4 = 8 elems
    for (int i = 0; i < 4; ++i) {
        int f = i * 256 + t;          // uint4 index; 32/row
        int row = f >> 5;
        int col = (f & 31) * 8;
        uint4 v = make_uint4(0u, 0u, 0u, 0u);
        if (n0 + row < NN) v = ((const uint4*)xin32)[(size_t)n0 * 32 + f];
        float2 p;
        p = bf2x(v.x); xs[row * 257 + col + 0] = p.x; xs[row * 257 + col + 1] = p.y;
        p = bf2x(v.y); xs[row * 257 + col + 2] = p.x; xs[row * 257 + col + 3] = p.y;
        p = bf2x(v.z); xs[row * 257 + col + 4] = p.x; xs[row * 257 + col + 5] = p.y;
        p = bf2x(v.w); xs[row * 257 + col + 6] = p.x; xs[row * 257 + col + 7] = p.y;
    }
    __syncthreads();
    int nl = t & 31;
    int cg = t >> 5;
    int c0 = cg * 5;
    float acc[5] = {0, 0, 0, 0, 0};
    for (int k = 0; k < 256; k += 4) {
        float x0 = xs[nl * 257 + k + 0];
        float x1 = xs[nl * 257 + k + 1];
        float x2 = xs[nl * 257 + k + 2];
        float x3 = xs[nl * 257 + k + 3];
#pragma unroll
        for (int i = 0; i < 5; ++i) {
            float4 w = *(const float4*)&W2T[(c0 + i) * 256 + k];
            acc[i] = fmaf(x0, w.x, acc[i]);
            acc[i] = fmaf(x1, w.y, acc[i]);
            acc[i] = fmaf(x2, w.z, acc[i]);
            acc[i] = fmaf(x3, w.w, acc[i]);
        }
    }
    float pa = 0.f, pb = 0.f;
#pragma unroll
    for (int i = 0; i < 5; ++i) {
        pa = fmaf(acc[i], al2[c0 + i], pa);
        pb = fmaf(acc[i], ar2[c0 + i], pb);
    }
    sel[cg][nl] = pa;
    ser[cg][nl] = pb;
    int node = n0 + nl;
    if (node < NN) {
#pragma unroll
        for (int i = 0; i < 5; ++i) h2[(size_t)node * 40 + c0 + i] = acc[i];
    }
    __syncthreads();
    if (t < 32) {
        float s = 0.f;
#pragma unroll
        for (int g = 0; g < 8; ++g) s += sel[g][t];
        if (n0 + t < NN) el2[n0 + t] = s;
    } else if (t < 64) {
        int n2 = t - 32;
        float s = 0.f;
#pragma unroll
        for (int g = 0; g < 8; ++g) s += ser[g][n2];
        if (n0 + n2 < NN) er2[n0 + n2] = s;
    }
}

// merged layer-2 softmax + aggregation: wave per dst
__global__ void k_agg2(const float* __restrict__ h2, const float* __restrict__ el2,
                       const float* __restrict__ er2, const float* __restrict__ b2,
                       const int* __restrict__ indptr, const int* __restrict__ srcs,
                       float* __restrict__ out) {
    __shared__ int   si[4][64];
    __shared__ float sw[4][64];
    int t = threadIdx.x;
    int wv = t >> 6, l = t & 63;
    int d = blockIdx.x * 4 + wv;
    int beg = indptr[d], end = indptr[d + 1];
    int deg = end - beg;
    float rd = er2[d];
    int s_l = 0;
    float w = 0.f;
    if (l < deg) {
        s_l = srcs[beg + l];
        float e = el2[s_l] + rd;
        e = e > 0.f ? e : 0.2f * e;
        w = __expf(e);
    }
    float sum = w;
    for (int j = beg + 64 + l; j < end; j += 64) {
        float e = el2[srcs[j]] + rd;
        e = e > 0.f ? e : 0.2f * e;
        sum += __expf(e);
    }
#pragma unroll
    for (int off = 32; off > 0; off >>= 1) sum += __shfl_xor(sum, off);
    float inv = sum > 0.f ? 1.f / sum : 0.f;
    si[wv][l] = s_l;
    sw[wv][l] = w * inv;
    float acc = 0.f;
    bool act = l < NCLS;
    int dege = deg < 64 ? deg : 64;
    for (int e = 0; e < dege; e += 4) {
        int ix0 = si[wv][e + 0];
        int ix1 = si[wv][e + 1];
        int ix2 = si[wv][e + 2];
        int ix3 = si[wv][e + 3];
        float w0 = sw[wv][e + 0];
        float w1 = sw[wv][e + 1];
        float w2 = sw[wv][e + 2];
        float w3 = sw[wv][e + 3];
        float v0 = act ? h2[(size_t)ix0 * NCLS + l] : 0.f;
        float v1 = act ? h2[(size_t)ix1 * NCLS + l] : 0.f;
        float v2 = act ? h2[(size_t)ix2 * NCLS + l] : 0.f;
        float v3 = act ? h2[(size_t)ix3 * NCLS + l] : 0.f;
        acc = fmaf(w0, v0, acc);
        acc = fmaf(w1, v1, acc);
        acc = fmaf(w2, v2, acc);
        acc = fmaf(w3, v3, acc);
    }
    for (int j = beg + 64; j < end; ++j) {     // deg>64 (rare)
        int s = srcs[j];
        float e = el2[s] + rd;
        e = e > 0.f ? e : 0.2f * e;
        float ww = __expf(e) * inv;
        float v = act ? h2[(size_t)s * NCLS + l] : 0.f;
        acc = fmaf(ww, v, acc);
    }
    if (act) out[(size_t)d * NCLS + l] = acc + b2[l];
}

extern "C" void kernel_launch(void* const* d_in, const int* in_sizes, int n_in,
                              void* d_out, int out_size, void* d_ws, size_t ws_size,
                              hipStream_t stream) {
    const float* x   = (const float*)d_in[0];
    const int*   src = (const int*)d_in[1];
    const int*   dst = (const int*)d_in[2];
    const float* W1  = (const float*)d_in[3];
    const float* al1 = (const float*)d_in[4];
    const float* ar1 = (const float*)d_in[5];
    const float* b1  = (const float*)d_in[6];
    const float* W2  = (const float*)d_in[7];
    const float* al2 = (const float*)d_in[8];
    const float* ar2 = (const float*)d_in[9];
    const float* b2  = (const float*)d_in[10];
    float* out = (float*)d_out;

    float* ws = (float*)d_ws;
    size_t off = 0;
    unsigned short* elu1 = (unsigned short*)(ws + off); off += (size_t)NN * 128;  // bf16 [N,256]
    unsigned short* xb   = (unsigned short*)(ws + off); off += (size_t)NN * 64;   // bf16 [N,128]
    float* h2   = ws + off; off += (size_t)NN * NCLS;
    float* el1  = ws + off; off += (size_t)NN * 4;
    float* er1  = ws + off; off += (size_t)NN * 4;
    float* el2  = ws + off; off += NN;
    float* er2  = ws + off; off += NN;
    float* wel  = ws + off; off += 512;
    float* wer  = ws + off; off += 512;
    float* w2t  = ws + off; off += (size_t)NCLS * 256;
    int* counts = (int*)(ws + off);
    int* indptr = counts + NN;
    int* fill   = indptr + NN + 1;
    int* srcs   = fill + NN;
    int* bsum   = srcs + NE;

    const int NB = (NN + 255) / 256;

    hipMemsetAsync(counts, 0, NN * sizeof(int), stream);

    k_count<<<(NE + 255) / 256, 256, 0, stream>>>(dst, counts);
    k_scanA<<<NB, 256, 0, stream>>>(counts, indptr, bsum);
    k_scanB<<<1, 256, 0, stream>>>(bsum, NB);
    k_scanC<<<NB, 256, 0, stream>>>(indptr, bsum, fill);
    k_scatter<<<(NE + 255) / 256, 256, 0, stream>>>(src, dst, indptr, fill, srcs);

    k_prep<<<1, 512, 0, stream>>>(W1, al1, ar1, W2, wel, wer, w2t);
    k_elr1x<<<(NN + 63) / 64, 256, 0, stream>>>(x, wel, wer, el1, er1, xb);
    k_fused1<<<NN / RPB, 256, 0, stream>>>((const unsigned int*)xb, W1, b1, el1, er1,
                                           indptr, srcs, elu1);

    k_gemm2<<<(NN + 31) / 32, 256, 0, stream>>>((const unsigned int*)elu1, w2t, al2, ar2,
                                                h2, el2, er2);
    k_agg2<<<NN / 4, 256, 0, stream>>>(h2, el2, er2, b2, indptr, srcs, out);
}

// Round 7
// 307.836 us; speedup vs baseline: 1.8851x; 1.0751x over previous
//
#include <hip/hip_runtime.h>

#define NN 50000
#define NE 800000
#define HID 256
#define NCLS 40

typedef short bf16x8 __attribute__((ext_vector_type(8)));
typedef float f32x4 __attribute__((ext_vector_type(4)));

__device__ inline unsigned short f2bf(float f) {            // RNE float->bf16
    unsigned int u = __float_as_uint(f);
    return (unsigned short)((u + 0x7FFFu + ((u >> 16) & 1u)) >> 16);
}
__device__ inline unsigned int pack2bf(float a, float b) {
    return (unsigned int)f2bf(a) | ((unsigned int)f2bf(b) << 16);
}
__device__ inline float2 bf2x(unsigned int u) {             // 2 bf16 -> 2 f32
    return make_float2(__uint_as_float(u << 16), __uint_as_float(u & 0xFFFF0000u));
}

// ---------------- CSR build ----------------
__global__ void k_count(const int* __restrict__ dst, int* __restrict__ counts) {
    int e = blockIdx.x * 256 + threadIdx.x;
    if (e < NE) atomicAdd(&counts[dst[e]], 1);
}

__global__ void k_scanA(const int* __restrict__ counts, int* __restrict__ indptr,
                        int* __restrict__ bsum) {
    __shared__ int sh[256];
    int t = threadIdx.x;
    int idx = blockIdx.x * 256 + t;
    int c = idx < NN ? counts[idx] : 0;
    sh[t] = c;
    __syncthreads();
    for (int off = 1; off < 256; off <<= 1) {
        int v = (t >= off) ? sh[t - off] : 0;
        __syncthreads();
        sh[t] += v;
        __syncthreads();
    }
    if (idx < NN) indptr[idx] = sh[t] - c;
    if (t == 255) bsum[blockIdx.x] = sh[255];
}

__global__ void k_scanB(int* __restrict__ bsum, int nb) {
    __shared__ int sh[256];
    int t = threadIdx.x;
    int c = t < nb ? bsum[t] : 0;
    sh[t] = c;
    __syncthreads();
    for (int off = 1; off < 256; off <<= 1) {
        int v = (t >= off) ? sh[t - off] : 0;
        __syncthreads();
        sh[t] += v;
        __syncthreads();
    }
    if (t < nb) bsum[t] = sh[t] - c;
}

__global__ void k_scanC(int* __restrict__ indptr, const int* __restrict__ bsum,
                        int* __restrict__ fill) {
    int idx = blockIdx.x * 256 + threadIdx.x;
    if (idx < NN) {
        indptr[idx] += bsum[idx >> 8];
        fill[idx] = 0;
    }
    if (idx == 0) indptr[NN] = NE;
}

__global__ void k_scatter(const int* __restrict__ src, const int* __restrict__ dst,
                          const int* __restrict__ indptr, int* __restrict__ fill,
                          int* __restrict__ srcs) {
    int e = blockIdx.x * 256 + threadIdx.x;
    if (e < NE) {
        int d = dst[e];
        int pos = atomicAdd(&fill[d], 1);
        srcs[indptr[d] + pos] = src[e];
    }
}

// ---------------- precompute: wel/wer + W1^T(bf16) + W2^T ----------------
__global__ void k_prep(const float* __restrict__ W1, const float* __restrict__ al,
                       const float* __restrict__ ar, const float* __restrict__ W2,
                       float* __restrict__ wel, float* __restrict__ wer,
                       unsigned short* __restrict__ W1Tb, float* __restrict__ W2T) {
    int gid = blockIdx.x * 256 + threadIdx.x;
    int nth = gridDim.x * 256;
    const int TOT = 512 + 32768 + 10240;
    for (int i = gid; i < TOT; i += nth) {
        if (i < 512) {
            int k = i >> 2, h = i & 3;
            float a = 0.f, b = 0.f;
            for (int dd = 0; dd < 64; ++dd) {
                float w = W1[k * 256 + h * 64 + dd];
                a = fmaf(w, al[h * 64 + dd], a);
                b = fmaf(w, ar[h * 64 + dd], b);
            }
            wel[i] = a;            // i == k*4+h
            wer[i] = b;
        } else if (i < 512 + 32768) {
            int j = i - 512;
            int col = j >> 7, k = j & 127;
            W1Tb[j] = f2bf(W1[k * 256 + col]);      // W1T [256 cols][128 k] bf16
        } else {
            int j = i - 512 - 32768;
            int c = j >> 8, kk = j & 255;
            W2T[j] = W2[kk * 40 + c];
        }
    }
}

// el1/er1[N,4] = x @ wel / x @ wer ; also emit bf16 copy of x
__global__ void k_elr1x(const float* __restrict__ x, const float* __restrict__ wel,
                        const float* __restrict__ wer, float* __restrict__ el1,
                        float* __restrict__ er1, unsigned short* __restrict__ xb) {
    __shared__ float xs[64 * 129];
    __shared__ float wels[512], wers[512];
    int t = threadIdx.x;
    int n0 = blockIdx.x * 64;
    wels[t] = wel[t]; wels[256 + t] = wel[256 + t];
    wers[t] = wer[t]; wers[256 + t] = wer[256 + t];
    for (int i = 0; i < 8; ++i) {
        int f = i * 256 + t;
        int row = f >> 5;
        int col4 = (f & 31) * 4;
        float4 v = make_float4(0.f, 0.f, 0.f, 0.f);
        if (n0 + row < NN) v = ((const float4*)x)[(size_t)n0 * 32 + f];
        xs[row * 129 + col4 + 0] = v.x;
        xs[row * 129 + col4 + 1] = v.y;
        xs[row * 129 + col4 + 2] = v.z;
        xs[row * 129 + col4 + 3] = v.w;
    }
    __syncthreads();
    int node = t & 63;
    int h = t >> 6;
    float a = 0.f, b = 0.f;
    for (int k = 0; k < 128; ++k) {
        float xv = xs[node * 129 + k];
        a = fmaf(xv, wels[k * 4 + h], a);
        b = fmaf(xv, wers[k * 4 + h], b);
    }
    if (n0 + node < NN) {
        el1[(size_t)(n0 + node) * 4 + h] = a;
        er1[(size_t)(n0 + node) * 4 + h] = b;
    }
    for (int i = 0; i < 4; ++i) {
        int g = (i * 256 + t) * 8;
        int row = g >> 7, col = g & 127;
        if (n0 + row < NN) {
            ushort4 lo, hi;
            lo.x = f2bf(xs[row * 129 + col + 0]);
            lo.y = f2bf(xs[row * 129 + col + 1]);
            lo.z = f2bf(xs[row * 129 + col + 2]);
            lo.w = f2bf(xs[row * 129 + col + 3]);
            hi.x = f2bf(xs[row * 129 + col + 4]);
            hi.y = f2bf(xs[row * 129 + col + 5]);
            hi.z = f2bf(xs[row * 129 + col + 6]);
            hi.w = f2bf(xs[row * 129 + col + 7]);
            *(ushort4*)&xb[(size_t)(n0 + row) * 128 + col] = lo;
            *(ushort4*)&xb[(size_t)(n0 + row) * 128 + col + 4] = hi;
        }
    }
}

// layer-1 aggregation only: in-register softmax + deep-MLP bf16 x-gather -> xaggb (bf16)
__global__ void k_agg1(const unsigned int* __restrict__ xb32,
                       const float* __restrict__ el1, const float* __restrict__ er1,
                       const int* __restrict__ indptr, const int* __restrict__ srcs,
                       unsigned int* __restrict__ xaggb) {
    __shared__ int   si[4][64];
    __shared__ float4 sw[4][64];
    int t = threadIdx.x;
    int wv = t >> 6, l = t & 63;
    int d = blockIdx.x * 4 + wv;
    int beg = indptr[d], end = indptr[d + 1];
    int deg = end - beg;
    float4 rd = *(const float4*)&er1[(size_t)d * 4];
    // ---- pass 1: weights (lane-parallel over edges) ----
    int s_l = 0;
    float4 w = make_float4(0.f, 0.f, 0.f, 0.f);
    if (l < deg) {
        s_l = srcs[beg + l];
        float4 ls = *(const float4*)&el1[(size_t)s_l * 4];
        float e0 = ls.x + rd.x, e1 = ls.y + rd.y, e2 = ls.z + rd.z, e3 = ls.w + rd.w;
        e0 = e0 > 0.f ? e0 : 0.2f * e0;
        e1 = e1 > 0.f ? e1 : 0.2f * e1;
        e2 = e2 > 0.f ? e2 : 0.2f * e2;
        e3 = e3 > 0.f ? e3 : 0.2f * e3;
        w = make_float4(__expf(e0), __expf(e1), __expf(e2), __expf(e3));
    }
    float s0 = w.x, s1 = w.y, s2 = w.z, s3 = w.w;
    for (int j = beg + 64 + l; j < end; j += 64) {     // deg>64 (rare)
        float4 ls = *(const float4*)&el1[(size_t)srcs[j] * 4];
        float e0 = ls.x + rd.x, e1 = ls.y + rd.y, e2 = ls.z + rd.z, e3 = ls.w + rd.w;
        e0 = e0 > 0.f ? e0 : 0.2f * e0;
        e1 = e1 > 0.f ? e1 : 0.2f * e1;
        e2 = e2 > 0.f ? e2 : 0.2f * e2;
        e3 = e3 > 0.f ? e3 : 0.2f * e3;
        s0 += __expf(e0); s1 += __expf(e1); s2 += __expf(e2); s3 += __expf(e3);
    }
#pragma unroll
    for (int off = 32; off > 0; off >>= 1) {
        s0 += __shfl_xor(s0, off);
        s1 += __shfl_xor(s1, off);
        s2 += __shfl_xor(s2, off);
        s3 += __shfl_xor(s3, off);
    }
    float i0 = s0 > 0.f ? 1.f / s0 : 0.f;
    float i1 = s1 > 0.f ? 1.f / s1 : 0.f;
    float i2 = s2 > 0.f ? 1.f / s2 : 0.f;
    float i3 = s3 > 0.f ? 1.f / s3 : 0.f;
    si[wv][l] = s_l;
    sw[wv][l] = make_float4(w.x * i0, w.y * i1, w.z * i2, w.w * i3);
    // ---- pass 2: bf16 x-gather, 4 independent rows in flight ----
    float2 a0 = {0.f, 0.f}, a1 = {0.f, 0.f}, a2 = {0.f, 0.f}, a3 = {0.f, 0.f};
    int dege = deg < 64 ? deg : 64;
    for (int e = 0; e < dege; e += 4) {
        int ix0 = si[wv][e + 0];
        int ix1 = si[wv][e + 1];
        int ix2 = si[wv][e + 2];
        int ix3 = si[wv][e + 3];
        float4 w0 = sw[wv][e + 0];
        float4 w1 = sw[wv][e + 1];
        float4 w2 = sw[wv][e + 2];
        float4 w3 = sw[wv][e + 3];
        unsigned int u0 = xb32[(size_t)ix0 * 64 + l];
        unsigned int u1 = xb32[(size_t)ix1 * 64 + l];
        unsigned int u2 = xb32[(size_t)ix2 * 64 + l];
        unsigned int u3 = xb32[(size_t)ix3 * 64 + l];
        float2 x0 = bf2x(u0);
        float2 x1 = bf2x(u1);
        float2 x2 = bf2x(u2);
        float2 x3 = bf2x(u3);
        a0.x = fmaf(w0.x, x0.x, a0.x); a0.y = fmaf(w0.x, x0.y, a0.y);
        a1.x = fmaf(w0.y, x0.x, a1.x); a1.y = fmaf(w0.y, x0.y, a1.y);
        a2.x = fmaf(w0.z, x0.x, a2.x); a2.y = fmaf(w0.z, x0.y, a2.y);
        a3.x = fmaf(w0.w, x0.x, a3.x); a3.y = fmaf(w0.w, x0.y, a3.y);
        a0.x = fmaf(w1.x, x1.x, a0.x); a0.y = fmaf(w1.x, x1.y, a0.y);
        a1.x = fmaf(w1.y, x1.x, a1.x); a1.y = fmaf(w1.y, x1.y, a1.y);
        a2.x = fmaf(w1.z, x1.x, a2.x); a2.y = fmaf(w1.z, x1.y, a2.y);
        a3.x = fmaf(w1.w, x1.x, a3.x); a3.y = fmaf(w1.w, x1.y, a3.y);
        a0.x = fmaf(w2.x, x2.x, a0.x); a0.y = fmaf(w2.x, x2.y, a0.y);
        a1.x = fmaf(w2.y, x2.x, a1.x); a1.y = fmaf(w2.y, x2.y, a1.y);
        a2.x = fmaf(w2.z, x2.x, a2.x); a2.y = fmaf(w2.z, x2.y, a2.y);
        a3.x = fmaf(w2.w, x2.x, a3.x); a3.y = fmaf(w2.w, x2.y, a3.y);
        a0.x = fmaf(w3.x, x3.x, a0.x); a0.y = fmaf(w3.x, x3.y, a0.y);
        a1.x = fmaf(w3.y, x3.x, a1.x); a1.y = fmaf(w3.y, x3.y, a1.y);
        a2.x = fmaf(w3.z, x3.x, a2.x); a2.y = fmaf(w3.z, x3.y, a2.y);
        a3.x = fmaf(w3.w, x3.x, a3.x); a3.y = fmaf(w3.w, x3.y, a3.y);
    }
    for (int j = beg + 64; j < end; ++j) {             // deg>64 (rare)
        int s = srcs[j];
        float4 ls = *(const float4*)&el1[(size_t)s * 4];
        float e0 = ls.x + rd.x, e1 = ls.y + rd.y, e2 = ls.z + rd.z, e3 = ls.w + rd.w;
        e0 = e0 > 0.f ? e0 : 0.2f * e0;
        e1 = e1 > 0.f ? e1 : 0.2f * e1;
        e2 = e2 > 0.f ? e2 : 0.2f * e2;
        e3 = e3 > 0.f ? e3 : 0.2f * e3;
        float w0 = __expf(e0) * i0, w1 = __expf(e1) * i1;
        float w2 = __expf(e2) * i2, w3 = __expf(e3) * i3;
        float2 xv = bf2x(xb32[(size_t)s * 64 + l]);
        a0.x = fmaf(w0, xv.x, a0.x); a0.y = fmaf(w0, xv.y, a0.y);
        a1.x = fmaf(w1, xv.x, a1.x); a1.y = fmaf(w1, xv.y, a1.y);
        a2.x = fmaf(w2, xv.x, a2.x); a2.y = fmaf(w2, xv.y, a2.y);
        a3.x = fmaf(w3, xv.x, a3.x); a3.y = fmaf(w3, xv.y, a3.y);
    }
    size_t base = (size_t)d * 256;   // dwords: [node][head][64]
    xaggb[base + 0 * 64 + l] = pack2bf(a0.x, a0.y);
    xaggb[base + 1 * 64 + l] = pack2bf(a1.x, a1.y);
    xaggb[base + 2 * 64 + l] = pack2bf(a2.x, a2.y);
    xaggb[base + 3 * 64 + l] = pack2bf(a3.x, a3.y);
}

// MFMA projection: elu1 = ELU(blockdiag(xagg @ W1_head) + b1), bf16 in/out
// wave: 16 nodes (rowgrp) x 2 heads (colgrp); 8 C-tiles of 16x16, K=128
__global__ void k_mfma1(const unsigned short* __restrict__ xaggb,
                        const unsigned short* __restrict__ W1Tb,
                        const float* __restrict__ b1,
                        unsigned short* __restrict__ elu1) {
    int t = threadIdx.x;
    int wv = t >> 6, l = t & 63;
    int rowgrp = wv >> 1, colgrp = wv & 1;
    int n0 = blockIdx.x * 32;
    int h0 = colgrp * 2;
    int lrow = l & 15, lk = l >> 4;
    f32x4 acc[8] = {};
    int arow = n0 + rowgrp * 16 + lrow;
    if (arow >= NN) arow = NN - 1;
#pragma unroll
    for (int kt = 0; kt < 4; ++kt) {
        int kofs = kt * 32 + lk * 8;
        bf16x8 a0v = *(const bf16x8*)&xaggb[((size_t)arow * 4 + h0) * 128 + kofs];
        bf16x8 a1v = *(const bf16x8*)&xaggb[((size_t)arow * 4 + h0 + 1) * 128 + kofs];
#pragma unroll
        for (int nt = 0; nt < 4; ++nt) {
            int col0 = (h0 + 0) * 64 + nt * 16 + lrow;
            bf16x8 bv0 = *(const bf16x8*)&W1Tb[(size_t)col0 * 128 + kofs];
            acc[nt] = __builtin_amdgcn_mfma_f32_16x16x32_bf16(a0v, bv0, acc[nt], 0, 0, 0);
            int col1 = (h0 + 1) * 64 + nt * 16 + lrow;
            bf16x8 bv1 = *(const bf16x8*)&W1Tb[(size_t)col1 * 128 + kofs];
            acc[4 + nt] = __builtin_amdgcn_mfma_f32_16x16x32_bf16(a1v, bv1, acc[4 + nt], 0, 0, 0);
        }
    }
#pragma unroll
    for (int ct = 0; ct < 8; ++ct) {
        int hh = ct >> 2, nt = ct & 3;
        int col = (h0 + hh) * 64 + nt * 16 + lrow;
        float bv = b1[col];
#pragma unroll
        for (int r = 0; r < 4; ++r) {
            int row = n0 + rowgrp * 16 + lk * 4 + r;
            if (row < NN) {
                float o = acc[ct][r] + bv;
                o = o > 0.f ? o : (__expf(o) - 1.f);
                elu1[(size_t)row * 256 + col] = f2bf(o);
            }
        }
    }
}

// ---------------- layer 2 ----------------
__global__ void k_gemm2(const unsigned int* __restrict__ xin32,
                        const float* __restrict__ W2T,
                        const float* __restrict__ al2, const float* __restrict__ ar2,
                        float* __restrict__ h2, float* __restrict__ el2,
                        float* __restrict__ er2) {
    __shared__ float xs[32 * 257];
    __shared__ float sel[8][32], ser[8][32];
    int t = threadIdx.x;
    int n0 = blockIdx.x * 32;
    for (int i = 0; i < 4; ++i) {
        int f = i * 256 + t;
        int row = f >> 5;
        int col = (f & 31) * 8;
        uint4 v = make_uint4(0u, 0u, 0u, 0u);
        if (n0 + row < NN) v = ((const uint4*)xin32)[(size_t)n0 * 32 + f];
        float2 p;
        p = bf2x(v.x); xs[row * 257 + col + 0] = p.x; xs[row * 257 + col + 1] = p.y;
        p = bf2x(v.y); xs[row * 257 + col + 2] = p.x; xs[row * 257 + col + 3] = p.y;
        p = bf2x(v.z); xs[row * 257 + col + 4] = p.x; xs[row * 257 + col + 5] = p.y;
        p = bf2x(v.w); xs[row * 257 + col + 6] = p.x; xs[row * 257 + col + 7] = p.y;
    }
    __syncthreads();
    int nl = t & 31;
    int cg = t >> 5;
    int c0 = cg * 5;
    float acc[5] = {0, 0, 0, 0, 0};
    for (int k = 0; k < 256; k += 4) {
        float x0 = xs[nl * 257 + k + 0];
        float x1 = xs[nl * 257 + k + 1];
        float x2 = xs[nl * 257 + k + 2];
        float x3 = xs[nl * 257 + k + 3];
#pragma unroll
        for (int i = 0; i < 5; ++i) {
            float4 w = *(const float4*)&W2T[(c0 + i) * 256 + k];
            acc[i] = fmaf(x0, w.x, acc[i]);
            acc[i] = fmaf(x1, w.y, acc[i]);
            acc[i] = fmaf(x2, w.z, acc[i]);
            acc[i] = fmaf(x3, w.w, acc[i]);
        }
    }
    float pa = 0.f, pb = 0.f;
#pragma unroll
    for (int i = 0; i < 5; ++i) {
        pa = fmaf(acc[i], al2[c0 + i], pa);
        pb = fmaf(acc[i], ar2[c0 + i], pb);
    }
    sel[cg][nl] = pa;
    ser[cg][nl] = pb;
    int node = n0 + nl;
    if (node < NN) {
#pragma unroll
        for (int i = 0; i < 5; ++i) h2[(size_t)node * 40 + c0 + i] = acc[i];
    }
    __syncthreads();
    if (t < 32) {
        float s = 0.f;
#pragma unroll
        for (int g = 0; g < 8; ++g) s += sel[g][t];
        if (n0 + t < NN) el2[n0 + t] = s;
    } else if (t < 64) {
        int n2 = t - 32;
        float s = 0.f;
#pragma unroll
        for (int g = 0; g < 8; ++g) s += ser[g][n2];
        if (n0 + n2 < NN) er2[n0 + n2] = s;
    }
}

// merged layer-2 softmax + aggregation: wave per dst
__global__ void k_agg2(const float* __restrict__ h2, const float* __restrict__ el2,
                       const float* __restrict__ er2, const float* __restrict__ b2,
                       const int* __restrict__ indptr, const int* __restrict__ srcs,
                       float* __restrict__ out) {
    __shared__ int   si[4][64];
    __shared__ float sw[4][64];
    int t = threadIdx.x;
    int wv = t >> 6, l = t & 63;
    int d = blockIdx.x * 4 + wv;
    int beg = indptr[d], end = indptr[d + 1];
    int deg = end - beg;
    float rd = er2[d];
    int s_l = 0;
    float w = 0.f;
    if (l < deg) {
        s_l = srcs[beg + l];
        float e = el2[s_l] + rd;
        e = e > 0.f ? e : 0.2f * e;
        w = __expf(e);
    }
    float sum = w;
    for (int j = beg + 64 + l; j < end; j += 64) {
        float e = el2[srcs[j]] + rd;
        e = e > 0.f ? e : 0.2f * e;
        sum += __expf(e);
    }
#pragma unroll
    for (int off = 32; off > 0; off >>= 1) sum += __shfl_xor(sum, off);
    float inv = sum > 0.f ? 1.f / sum : 0.f;
    si[wv][l] = s_l;
    sw[wv][l] = w * inv;
    float acc = 0.f;
    bool act = l < NCLS;
    int dege = deg < 64 ? deg : 64;
    for (int e = 0; e < dege; e += 4) {
        int ix0 = si[wv][e + 0];
        int ix1 = si[wv][e + 1];
        int ix2 = si[wv][e + 2];
        int ix3 = si[wv][e + 3];
        float w0 = sw[wv][e + 0];
        float w1 = sw[wv][e + 1];
        float w2 = sw[wv][e + 2];
        float w3 = sw[wv][e + 3];
        float v0 = act ? h2[(size_t)ix0 * NCLS + l] : 0.f;
        float v1 = act ? h2[(size_t)ix1 * NCLS + l] : 0.f;
        float v2 = act ? h2[(size_t)ix2 * NCLS + l] : 0.f;
        float v3 = act ? h2[(size_t)ix3 * NCLS + l] : 0.f;
        acc = fmaf(w0, v0, acc);
        acc = fmaf(w1, v1, acc);
        acc = fmaf(w2, v2, acc);
        acc = fmaf(w3, v3, acc);
    }
    for (int j = beg + 64; j < end; ++j) {
        int s = srcs[j];
        float e = el2[s] + rd;
        e = e > 0.f ? e : 0.2f * e;
        float ww = __expf(e) * inv;
        float v = act ? h2[(size_t)s * NCLS + l] : 0.f;
        acc = fmaf(ww, v, acc);
    }
    if (act) out[(size_t)d * NCLS + l] = acc + b2[l];
}

extern "C" void kernel_launch(void* const* d_in, const int* in_sizes, int n_in,
                              void* d_out, int out_size, void* d_ws, size_t ws_size,
                              hipStream_t stream) {
    const float* x   = (const float*)d_in[0];
    const int*   src = (const int*)d_in[1];
    const int*   dst = (const int*)d_in[2];
    const float* W1  = (const float*)d_in[3];
    const float* al1 = (const float*)d_in[4];
    const float* ar1 = (const float*)d_in[5];
    const float* b1  = (const float*)d_in[6];
    const float* W2  = (const float*)d_in[7];
    const float* al2 = (const float*)d_in[8];
    const float* ar2 = (const float*)d_in[9];
    const float* b2  = (const float*)d_in[10];
    float* out = (float*)d_out;

    float* ws = (float*)d_ws;
    size_t off = 0;
    unsigned short* elu1  = (unsigned short*)(ws + off); off += (size_t)NN * 128; // bf16 [N,256]
    unsigned short* xb    = (unsigned short*)(ws + off); off += (size_t)NN * 64;  // bf16 [N,128]
    unsigned short* xaggb = (unsigned short*)(ws + off); off += (size_t)NN * 256; // bf16 [N,4,128]
    float* h2   = ws + off; off += (size_t)NN * NCLS;
    float* el1  = ws + off; off += (size_t)NN * 4;
    float* er1  = ws + off; off += (size_t)NN * 4;
    float* el2  = ws + off; off += NN;
    float* er2  = ws + off; off += NN;
    float* wel  = ws + off; off += 512;
    float* wer  = ws + off; off += 512;
    unsigned short* w1tb = (unsigned short*)(ws + off); off += 16384;             // bf16 [256,128]
    float* w2t  = ws + off; off += (size_t)NCLS * 256;
    int* counts = (int*)(ws + off);
    int* indptr = counts + NN;
    int* fill   = indptr + NN + 1;
    int* srcs   = fill + NN;
    int* bsum   = srcs + NE;

    const int NB = (NN + 255) / 256;

    hipMemsetAsync(counts, 0, NN * sizeof(int), stream);

    k_count<<<(NE + 255) / 256, 256, 0, stream>>>(dst, counts);
    k_scanA<<<NB, 256, 0, stream>>>(counts, indptr, bsum);
    k_scanB<<<1, 256, 0, stream>>>(bsum, NB);
    k_scanC<<<NB, 256, 0, stream>>>(indptr, bsum, fill);
    k_scatter<<<(NE + 255) / 256, 256, 0, stream>>>(src, dst, indptr, fill, srcs);

    k_prep<<<48, 256, 0, stream>>>(W1, al1, ar1, W2, wel, wer, w1tb, w2t);
    k_elr1x<<<(NN + 63) / 64, 256, 0, stream>>>(x, wel, wer, el1, er1, xb);
    k_agg1<<<NN / 4, 256, 0, stream>>>((const unsigned int*)xb, el1, er1, indptr, srcs,
                                       (unsigned int*)xaggb);
    k_mfma1<<<(NN + 31) / 32, 256, 0, stream>>>(xaggb, w1tb, b1, elu1);

    k_gemm2<<<(NN + 31) / 32, 256, 0, stream>>>((const unsigned int*)elu1, w2t, al2, ar2,
                                                h2, el2, er2);
    k_agg2<<<NN / 4, 256, 0, stream>>>(h2, el2, er2, b2, indptr, srcs, out);
}

// Round 8
// 266.109 us; speedup vs baseline: 2.1807x; 1.1568x over previous
//
#include <hip/hip_runtime.h>

#define NN 50000
#define NE 800000
#define HID 256
#define NCLS 40

typedef short bf16x8 __attribute__((ext_vector_type(8)));
typedef float f32x4 __attribute__((ext_vector_type(4)));

__device__ inline unsigned short f2bf(float f) {            // RNE float->bf16
    unsigned int u = __float_as_uint(f);
    return (unsigned short)((u + 0x7FFFu + ((u >> 16) & 1u)) >> 16);
}
__device__ inline unsigned int pack2bf(float a, float b) {
    return (unsigned int)f2bf(a) | ((unsigned int)f2bf(b) << 16);
}
__device__ inline float2 bf2x(unsigned int u) {             // 2 bf16 -> 2 f32
    return make_float2(__uint_as_float(u << 16), __uint_as_float(u & 0xFFFF0000u));
}
__device__ inline float bf1(unsigned short u) {
    return __uint_as_float((unsigned int)u << 16);
}

// ---------------- CSR build ----------------
__global__ void k_count(const int* __restrict__ dst, int* __restrict__ counts) {
    int e = blockIdx.x * 256 + threadIdx.x;
    if (e < NE) atomicAdd(&counts[dst[e]], 1);
}

__global__ void k_scanA(const int* __restrict__ counts, int* __restrict__ indptr,
                        int* __restrict__ bsum) {
    __shared__ int sh[256];
    int t = threadIdx.x;
    int idx = blockIdx.x * 256 + t;
    int c = idx < NN ? counts[idx] : 0;
    sh[t] = c;
    __syncthreads();
    for (int off = 1; off < 256; off <<= 1) {
        int v = (t >= off) ? sh[t - off] : 0;
        __syncthreads();
        sh[t] += v;
        __syncthreads();
    }
    if (idx < NN) indptr[idx] = sh[t] - c;
    if (t == 255) bsum[blockIdx.x] = sh[255];
}

__global__ void k_scanB(int* __restrict__ bsum, int nb) {
    __shared__ int sh[256];
    int t = threadIdx.x;
    int c = t < nb ? bsum[t] : 0;
    sh[t] = c;
    __syncthreads();
    for (int off = 1; off < 256; off <<= 1) {
        int v = (t >= off) ? sh[t - off] : 0;
        __syncthreads();
        sh[t] += v;
        __syncthreads();
    }
    if (t < nb) bsum[t] = sh[t] - c;
}

__global__ void k_scanC(int* __restrict__ indptr, const int* __restrict__ bsum,
                        int* __restrict__ fill) {
    int idx = blockIdx.x * 256 + threadIdx.x;
    if (idx < NN) {
        indptr[idx] += bsum[idx >> 8];
        fill[idx] = 0;
    }
    if (idx == 0) indptr[NN] = NE;
}

__global__ void k_scatter(const int* __restrict__ src, const int* __restrict__ dst,
                          const int* __restrict__ indptr, int* __restrict__ fill,
                          int* __restrict__ srcs) {
    int e = blockIdx.x * 256 + threadIdx.x;
    if (e < NE) {
        int d = dst[e];
        int pos = atomicAdd(&fill[d], 1);
        srcs[indptr[d] + pos] = src[e];
    }
}

// ---------------- precompute: wel/wer + W1^T(bf16) + W2^T(bf16, 48 cols) ----------------
__global__ void k_prep(const float* __restrict__ W1, const float* __restrict__ al,
                       const float* __restrict__ ar, const float* __restrict__ W2,
                       float* __restrict__ wel, float* __restrict__ wer,
                       unsigned short* __restrict__ W1Tb,
                       unsigned short* __restrict__ W2Tb) {
    int gid = blockIdx.x * 256 + threadIdx.x;
    int nth = gridDim.x * 256;
    const int TOT = 512 + 32768 + 48 * 256;
    for (int i = gid; i < TOT; i += nth) {
        if (i < 512) {
            int k = i >> 2, h = i & 3;
            float a = 0.f, b = 0.f;
            for (int dd = 0; dd < 64; ++dd) {
                float w = W1[k * 256 + h * 64 + dd];
                a = fmaf(w, al[h * 64 + dd], a);
                b = fmaf(w, ar[h * 64 + dd], b);
            }
            wel[i] = a;            // i == k*4+h
            wer[i] = b;
        } else if (i < 512 + 32768) {
            int j = i - 512;
            int col = j >> 7, k = j & 127;
            W1Tb[j] = f2bf(W1[k * 256 + col]);      // W1T [256 cols][128 k] bf16
        } else {
            int j = i - 512 - 32768;
            int col = j >> 8, kk = j & 255;         // [48 cols][256 k]
            W2Tb[j] = (col < NCLS) ? f2bf(W2[kk * 40 + col]) : (unsigned short)0;
        }
    }
}

// el1/er1[N,4] = x @ wel / x @ wer ; also emit bf16 copy of x
__global__ void k_elr1x(const float* __restrict__ x, const float* __restrict__ wel,
                        const float* __restrict__ wer, float* __restrict__ el1,
                        float* __restrict__ er1, unsigned short* __restrict__ xb) {
    __shared__ float xs[64 * 129];
    __shared__ float wels[512], wers[512];
    int t = threadIdx.x;
    int n0 = blockIdx.x * 64;
    wels[t] = wel[t]; wels[256 + t] = wel[256 + t];
    wers[t] = wer[t]; wers[256 + t] = wer[256 + t];
    for (int i = 0; i < 8; ++i) {
        int f = i * 256 + t;
        int row = f >> 5;
        int col4 = (f & 31) * 4;
        float4 v = make_float4(0.f, 0.f, 0.f, 0.f);
        if (n0 + row < NN) v = ((const float4*)x)[(size_t)n0 * 32 + f];
        xs[row * 129 + col4 + 0] = v.x;
        xs[row * 129 + col4 + 1] = v.y;
        xs[row * 129 + col4 + 2] = v.z;
        xs[row * 129 + col4 + 3] = v.w;
    }
    __syncthreads();
    int node = t & 63;
    int h = t >> 6;
    float a = 0.f, b = 0.f;
    for (int k = 0; k < 128; ++k) {
        float xv = xs[node * 129 + k];
        a = fmaf(xv, wels[k * 4 + h], a);
        b = fmaf(xv, wers[k * 4 + h], b);
    }
    if (n0 + node < NN) {
        el1[(size_t)(n0 + node) * 4 + h] = a;
        er1[(size_t)(n0 + node) * 4 + h] = b;
    }
    for (int i = 0; i < 4; ++i) {
        int g = (i * 256 + t) * 8;
        int row = g >> 7, col = g & 127;
        if (n0 + row < NN) {
            ushort4 lo, hi;
            lo.x = f2bf(xs[row * 129 + col + 0]);
            lo.y = f2bf(xs[row * 129 + col + 1]);
            lo.z = f2bf(xs[row * 129 + col + 2]);
            lo.w = f2bf(xs[row * 129 + col + 3]);
            hi.x = f2bf(xs[row * 129 + col + 4]);
            hi.y = f2bf(xs[row * 129 + col + 5]);
            hi.z = f2bf(xs[row * 129 + col + 6]);
            hi.w = f2bf(xs[row * 129 + col + 7]);
            *(ushort4*)&xb[(size_t)(n0 + row) * 128 + col] = lo;
            *(ushort4*)&xb[(size_t)(n0 + row) * 128 + col + 4] = hi;
        }
    }
}

// layer-1 aggregation only: in-register softmax + deep-MLP bf16 x-gather -> xaggb (bf16)
__global__ void k_agg1(const unsigned int* __restrict__ xb32,
                       const float* __restrict__ el1, const float* __restrict__ er1,
                       const int* __restrict__ indptr, const int* __restrict__ srcs,
                       unsigned int* __restrict__ xaggb) {
    __shared__ int   si[4][64];
    __shared__ float4 sw[4][64];
    int t = threadIdx.x;
    int wv = t >> 6, l = t & 63;
    int d = blockIdx.x * 4 + wv;
    int beg = indptr[d], end = indptr[d + 1];
    int deg = end - beg;
    float4 rd = *(const float4*)&er1[(size_t)d * 4];
    // ---- pass 1: weights (lane-parallel over edges) ----
    int s_l = 0;
    float4 w = make_float4(0.f, 0.f, 0.f, 0.f);
    if (l < deg) {
        s_l = srcs[beg + l];
        float4 ls = *(const float4*)&el1[(size_t)s_l * 4];
        float e0 = ls.x + rd.x, e1 = ls.y + rd.y, e2 = ls.z + rd.z, e3 = ls.w + rd.w;
        e0 = e0 > 0.f ? e0 : 0.2f * e0;
        e1 = e1 > 0.f ? e1 : 0.2f * e1;
        e2 = e2 > 0.f ? e2 : 0.2f * e2;
        e3 = e3 > 0.f ? e3 : 0.2f * e3;
        w = make_float4(__expf(e0), __expf(e1), __expf(e2), __expf(e3));
    }
    float s0 = w.x, s1 = w.y, s2 = w.z, s3 = w.w;
    for (int j = beg + 64 + l; j < end; j += 64) {     // deg>64 (rare)
        float4 ls = *(const float4*)&el1[(size_t)srcs[j] * 4];
        float e0 = ls.x + rd.x, e1 = ls.y + rd.y, e2 = ls.z + rd.z, e3 = ls.w + rd.w;
        e0 = e0 > 0.f ? e0 : 0.2f * e0;
        e1 = e1 > 0.f ? e1 : 0.2f * e1;
        e2 = e2 > 0.f ? e2 : 0.2f * e2;
        e3 = e3 > 0.f ? e3 : 0.2f * e3;
        s0 += __expf(e0); s1 += __expf(e1); s2 += __expf(e2); s3 += __expf(e3);
    }
#pragma unroll
    for (int off = 32; off > 0; off >>= 1) {
        s0 += __shfl_xor(s0, off);
        s1 += __shfl_xor(s1, off);
        s2 += __shfl_xor(s2, off);
        s3 += __shfl_xor(s3, off);
    }
    float i0 = s0 > 0.f ? 1.f / s0 : 0.f;
    float i1 = s1 > 0.f ? 1.f / s1 : 0.f;
    float i2 = s2 > 0.f ? 1.f / s2 : 0.f;
    float i3 = s3 > 0.f ? 1.f / s3 : 0.f;
    si[wv][l] = s_l;
    sw[wv][l] = make_float4(w.x * i0, w.y * i1, w.z * i2, w.w * i3);
    // ---- pass 2: bf16 x-gather, 4 independent rows in flight ----
    float2 a0 = {0.f, 0.f}, a1 = {0.f, 0.f}, a2 = {0.f, 0.f}, a3 = {0.f, 0.f};
    int dege = deg < 64 ? deg : 64;
    for (int e = 0; e < dege; e += 4) {
        int ix0 = si[wv][e + 0];
        int ix1 = si[wv][e + 1];
        int ix2 = si[wv][e + 2];
        int ix3 = si[wv][e + 3];
        float4 w0 = sw[wv][e + 0];
        float4 w1 = sw[wv][e + 1];
        float4 w2 = sw[wv][e + 2];
        float4 w3 = sw[wv][e + 3];
        unsigned int u0 = xb32[(size_t)ix0 * 64 + l];
        unsigned int u1 = xb32[(size_t)ix1 * 64 + l];
        unsigned int u2 = xb32[(size_t)ix2 * 64 + l];
        unsigned int u3 = xb32[(size_t)ix3 * 64 + l];
        float2 x0 = bf2x(u0);
        float2 x1 = bf2x(u1);
        float2 x2 = bf2x(u2);
        float2 x3 = bf2x(u3);
        a0.x = fmaf(w0.x, x0.x, a0.x); a0.y = fmaf(w0.x, x0.y, a0.y);
        a1.x = fmaf(w0.y, x0.x, a1.x); a1.y = fmaf(w0.y, x0.y, a1.y);
        a2.x = fmaf(w0.z, x0.x, a2.x); a2.y = fmaf(w0.z, x0.y, a2.y);
        a3.x = fmaf(w0.w, x0.x, a3.x); a3.y = fmaf(w0.w, x0.y, a3.y);
        a0.x = fmaf(w1.x, x1.x, a0.x); a0.y = fmaf(w1.x, x1.y, a0.y);
        a1.x = fmaf(w1.y, x1.x, a1.x); a1.y = fmaf(w1.y, x1.y, a1.y);
        a2.x = fmaf(w1.z, x1.x, a2.x); a2.y = fmaf(w1.z, x1.y, a2.y);
        a3.x = fmaf(w1.w, x1.x, a3.x); a3.y = fmaf(w1.w, x1.y, a3.y);
        a0.x = fmaf(w2.x, x2.x, a0.x); a0.y = fmaf(w2.x, x2.y, a0.y);
        a1.x = fmaf(w2.y, x2.x, a1.x); a1.y = fmaf(w2.y, x2.y, a1.y);
        a2.x = fmaf(w2.z, x2.x, a2.x); a2.y = fmaf(w2.z, x2.y, a2.y);
        a3.x = fmaf(w2.w, x2.x, a3.x); a3.y = fmaf(w2.w, x2.y, a3.y);
        a0.x = fmaf(w3.x, x3.x, a0.x); a0.y = fmaf(w3.x, x3.y, a0.y);
        a1.x = fmaf(w3.y, x3.x, a1.x); a1.y = fmaf(w3.y, x3.y, a1.y);
        a2.x = fmaf(w3.z, x3.x, a2.x); a2.y = fmaf(w3.z, x3.y, a2.y);
        a3.x = fmaf(w3.w, x3.x, a3.x); a3.y = fmaf(w3.w, x3.y, a3.y);
    }
    for (int j = beg + 64; j < end; ++j) {             // deg>64 (rare)
        int s = srcs[j];
        float4 ls = *(const float4*)&el1[(size_t)s * 4];
        float e0 = ls.x + rd.x, e1 = ls.y + rd.y, e2 = ls.z + rd.z, e3 = ls.w + rd.w;
        e0 = e0 > 0.f ? e0 : 0.2f * e0;
        e1 = e1 > 0.f ? e1 : 0.2f * e1;
        e2 = e2 > 0.f ? e2 : 0.2f * e2;
        e3 = e3 > 0.f ? e3 : 0.2f * e3;
        float w0 = __expf(e0) * i0, w1 = __expf(e1) * i1;
        float w2 = __expf(e2) * i2, w3 = __expf(e3) * i3;
        float2 xv = bf2x(xb32[(size_t)s * 64 + l]);
        a0.x = fmaf(w0, xv.x, a0.x); a0.y = fmaf(w0, xv.y, a0.y);
        a1.x = fmaf(w1, xv.x, a1.x); a1.y = fmaf(w1, xv.y, a1.y);
        a2.x = fmaf(w2, xv.x, a2.x); a2.y = fmaf(w2, xv.y, a2.y);
        a3.x = fmaf(w3, xv.x, a3.x); a3.y = fmaf(w3, xv.y, a3.y);
    }
    size_t base = (size_t)d * 256;   // dwords: [node][head][64]
    xaggb[base + 0 * 64 + l] = pack2bf(a0.x, a0.y);
    xaggb[base + 1 * 64 + l] = pack2bf(a1.x, a1.y);
    xaggb[base + 2 * 64 + l] = pack2bf(a2.x, a2.y);
    xaggb[base + 3 * 64 + l] = pack2bf(a3.x, a3.y);
}

// MFMA projection: elu1 = ELU(blockdiag(xagg @ W1_head) + b1), bf16 in/out
__global__ void k_mfma1(const unsigned short* __restrict__ xaggb,
                        const unsigned short* __restrict__ W1Tb,
                        const float* __restrict__ b1,
                        unsigned short* __restrict__ elu1) {
    int t = threadIdx.x;
    int wv = t >> 6, l = t & 63;
    int rowgrp = wv >> 1, colgrp = wv & 1;
    int n0 = blockIdx.x * 32;
    int h0 = colgrp * 2;
    int lrow = l & 15, lk = l >> 4;
    f32x4 acc[8] = {};
    int arow = n0 + rowgrp * 16 + lrow;
    if (arow >= NN) arow = NN - 1;
#pragma unroll
    for (int kt = 0; kt < 4; ++kt) {
        int kofs = kt * 32 + lk * 8;
        bf16x8 a0v = *(const bf16x8*)&xaggb[((size_t)arow * 4 + h0) * 128 + kofs];
        bf16x8 a1v = *(const bf16x8*)&xaggb[((size_t)arow * 4 + h0 + 1) * 128 + kofs];
#pragma unroll
        for (int nt = 0; nt < 4; ++nt) {
            int col0 = (h0 + 0) * 64 + nt * 16 + lrow;
            bf16x8 bv0 = *(const bf16x8*)&W1Tb[(size_t)col0 * 128 + kofs];
            acc[nt] = __builtin_amdgcn_mfma_f32_16x16x32_bf16(a0v, bv0, acc[nt], 0, 0, 0);
            int col1 = (h0 + 1) * 64 + nt * 16 + lrow;
            bf16x8 bv1 = *(const bf16x8*)&W1Tb[(size_t)col1 * 128 + kofs];
            acc[4 + nt] = __builtin_amdgcn_mfma_f32_16x16x32_bf16(a1v, bv1, acc[4 + nt], 0, 0, 0);
        }
    }
#pragma unroll
    for (int ct = 0; ct < 8; ++ct) {
        int hh = ct >> 2, nt = ct & 3;
        int col = (h0 + hh) * 64 + nt * 16 + lrow;
        float bv = b1[col];
#pragma unroll
        for (int r = 0; r < 4; ++r) {
            int row = n0 + rowgrp * 16 + lk * 4 + r;
            if (row < NN) {
                float o = acc[ct][r] + bv;
                o = o > 0.f ? o : (__expf(o) - 1.f);
                elu1[(size_t)row * 256 + col] = f2bf(o);
            }
        }
    }
}

// ---------------- layer 2: MFMA GEMM [N,256]@[256,48] + fused el2/er2 ----------------
// wave = 16 nodes; 3 col tiles (cols 0..47, 40..47 are zero-padded W2)
__global__ void k_mfma2(const unsigned short* __restrict__ elu1,
                        const unsigned short* __restrict__ W2Tb,
                        const float* __restrict__ al2, const float* __restrict__ ar2,
                        unsigned short* __restrict__ h2b, float* __restrict__ el2,
                        float* __restrict__ er2) {
    int t = threadIdx.x;
    int wv = t >> 6, l = t & 63;
    int lrow = l & 15, lk = l >> 4;
    int n0 = blockIdx.x * 64 + wv * 16;
    int arow = n0 + lrow;
    if (arow >= NN) arow = NN - 1;
    f32x4 acc[3] = {};
#pragma unroll
    for (int kt = 0; kt < 8; ++kt) {
        int kofs = kt * 32 + lk * 8;
        bf16x8 av = *(const bf16x8*)&elu1[(size_t)arow * 256 + kofs];
#pragma unroll
        for (int nt = 0; nt < 3; ++nt) {
            bf16x8 bv = *(const bf16x8*)&W2Tb[(size_t)(nt * 16 + lrow) * 256 + kofs];
            acc[nt] = __builtin_amdgcn_mfma_f32_16x16x32_bf16(av, bv, acc[nt], 0, 0, 0);
        }
    }
    // per-lane al2/ar2 coefficients for its 3 columns
    float alc[3], arc[3];
#pragma unroll
    for (int nt = 0; nt < 3; ++nt) {
        int col = nt * 16 + lrow;
        alc[nt] = col < NCLS ? al2[col] : 0.f;
        arc[nt] = col < NCLS ? ar2[col] : 0.f;
    }
#pragma unroll
    for (int r = 0; r < 4; ++r) {
        int row = n0 + lk * 4 + r;
        float pa = 0.f, pb = 0.f;
#pragma unroll
        for (int nt = 0; nt < 3; ++nt) {
            float v = acc[nt][r];
            pa = fmaf(v, alc[nt], pa);
            pb = fmaf(v, arc[nt], pb);
            int col = nt * 16 + lrow;
            if (row < NN && col < NCLS) h2b[(size_t)row * NCLS + col] = f2bf(v);
        }
#pragma unroll
        for (int off = 1; off < 16; off <<= 1) {
            pa += __shfl_xor(pa, off);
            pb += __shfl_xor(pb, off);
        }
        if (lrow == 0 && row < NN) {
            el2[row] = pa;
            er2[row] = pb;
        }
    }
}

// merged layer-2 softmax + aggregation: wave per dst (h2 in bf16)
__global__ void k_agg2(const unsigned short* __restrict__ h2b,
                       const float* __restrict__ el2,
                       const float* __restrict__ er2, const float* __restrict__ b2,
                       const int* __restrict__ indptr, const int* __restrict__ srcs,
                       float* __restrict__ out) {
    __shared__ int   si[4][64];
    __shared__ float sw[4][64];
    int t = threadIdx.x;
    int wv = t >> 6, l = t & 63;
    int d = blockIdx.x * 4 + wv;
    int beg = indptr[d], end = indptr[d + 1];
    int deg = end - beg;
    float rd = er2[d];
    int s_l = 0;
    float w = 0.f;
    if (l < deg) {
        s_l = srcs[beg + l];
        float e = el2[s_l] + rd;
        e = e > 0.f ? e : 0.2f * e;
        w = __expf(e);
    }
    float sum = w;
    for (int j = beg + 64 + l; j < end; j += 64) {
        float e = el2[srcs[j]] + rd;
        e = e > 0.f ? e : 0.2f * e;
        sum += __expf(e);
    }
#pragma unroll
    for (int off = 32; off > 0; off >>= 1) sum += __shfl_xor(sum, off);
    float inv = sum > 0.f ? 1.f / sum : 0.f;
    si[wv][l] = s_l;
    sw[wv][l] = w * inv;
    float acc = 0.f;
    bool act = l < NCLS;
    int dege = deg < 64 ? deg : 64;
    for (int e = 0; e < dege; e += 4) {
        int ix0 = si[wv][e + 0];
        int ix1 = si[wv][e + 1];
        int ix2 = si[wv][e + 2];
        int ix3 = si[wv][e + 3];
        float w0 = sw[wv][e + 0];
        float w1 = sw[wv][e + 1];
        float w2 = sw[wv][e + 2];
        float w3 = sw[wv][e + 3];
        float v0 = act ? bf1(h2b[(size_t)ix0 * NCLS + l]) : 0.f;
        float v1 = act ? bf1(h2b[(size_t)ix1 * NCLS + l]) : 0.f;
        float v2 = act ? bf1(h2b[(size_t)ix2 * NCLS + l]) : 0.f;
        float v3 = act ? bf1(h2b[(size_t)ix3 * NCLS + l]) : 0.f;
        acc = fmaf(w0, v0, acc);
        acc = fmaf(w1, v1, acc);
        acc = fmaf(w2, v2, acc);
        acc = fmaf(w3, v3, acc);
    }
    for (int j = beg + 64; j < end; ++j) {
        int s = srcs[j];
        float e = el2[s] + rd;
        e = e > 0.f ? e : 0.2f * e;
        float ww = __expf(e) * inv;
        float v = act ? bf1(h2b[(size_t)s * NCLS + l]) : 0.f;
        acc = fmaf(ww, v, acc);
    }
    if (act) out[(size_t)d * NCLS + l] = acc + b2[l];
}

extern "C" void kernel_launch(void* const* d_in, const int* in_sizes, int n_in,
                              void* d_out, int out_size, void* d_ws, size_t ws_size,
                              hipStream_t stream) {
    const float* x   = (const float*)d_in[0];
    const int*   src = (const int*)d_in[1];
    const int*   dst = (const int*)d_in[2];
    const float* W1  = (const float*)d_in[3];
    const float* al1 = (const float*)d_in[4];
    const float* ar1 = (const float*)d_in[5];
    const float* b1  = (const float*)d_in[6];
    const float* W2  = (const float*)d_in[7];
    const float* al2 = (const float*)d_in[8];
    const float* ar2 = (const float*)d_in[9];
    const float* b2  = (const float*)d_in[10];
    float* out = (float*)d_out;

    float* ws = (float*)d_ws;
    size_t off = 0;
    unsigned short* elu1  = (unsigned short*)(ws + off); off += (size_t)NN * 128; // bf16 [N,256]
    unsigned short* xb    = (unsigned short*)(ws + off); off += (size_t)NN * 64;  // bf16 [N,128]
    unsigned short* xaggb = (unsigned short*)(ws + off); off += (size_t)NN * 256; // bf16 [N,4,128]
    unsigned short* h2b   = (unsigned short*)(ws + off); off += (size_t)NN * 20;  // bf16 [N,40]
    float* el1  = ws + off; off += (size_t)NN * 4;
    float* er1  = ws + off; off += (size_t)NN * 4;
    float* el2  = ws + off; off += NN;
    float* er2  = ws + off; off += NN;
    float* wel  = ws + off; off += 512;
    float* wer  = ws + off; off += 512;
    unsigned short* w1tb = (unsigned short*)(ws + off); off += 16384;             // bf16 [256,128]
    unsigned short* w2tb = (unsigned short*)(ws + off); off += 48 * 128;          // bf16 [48,256]
    int* counts = (int*)(ws + off);
    int* indptr = counts + NN;
    int* fill   = indptr + NN + 1;
    int* srcs   = fill + NN;
    int* bsum   = srcs + NE;

    const int NB = (NN + 255) / 256;

    hipMemsetAsync(counts, 0, NN * sizeof(int), stream);

    k_count<<<(NE + 255) / 256, 256, 0, stream>>>(dst, counts);
    k_scanA<<<NB, 256, 0, stream>>>(counts, indptr, bsum);
    k_scanB<<<1, 256, 0, stream>>>(bsum, NB);
    k_scanC<<<NB, 256, 0, stream>>>(indptr, bsum, fill);
    k_scatter<<<(NE + 255) / 256, 256, 0, stream>>>(src, dst, indptr, fill, srcs);

    k_prep<<<48, 256, 0, stream>>>(W1, al1, ar1, W2, wel, wer, w1tb, w2tb);
    k_elr1x<<<(NN + 63) / 64, 256, 0, stream>>>(x, wel, wer, el1, er1, xb);
    k_agg1<<<NN / 4, 256, 0, stream>>>((const unsigned int*)xb, el1, er1, indptr, srcs,
                                       (unsigned int*)xaggb);
    k_mfma1<<<(NN + 31) / 32, 256, 0, stream>>>(xaggb, w1tb, b1, elu1);

    k_mfma2<<<(NN + 63) / 64, 256, 0, stream>>>(elu1, w2tb, al2, ar2, h2b, el2, er2);
    k_agg2<<<NN / 4, 256, 0, stream>>>(h2b, el2, er2, b2, indptr, srcs, out);
}

// Round 9
// 236.638 us; speedup vs baseline: 2.4523x; 1.1245x over previous
//
#include <hip/hip_runtime.h>

#define NN 50000
#define NE 800000
#define HID 256
#define NCLS 40

typedef short bf16x8 __attribute__((ext_vector_type(8)));
typedef float f32x4 __attribute__((ext_vector_type(4)));

__device__ inline unsigned short f2bf(float f) {            // RNE float->bf16
    unsigned int u = __float_as_uint(f);
    return (unsigned short)((u + 0x7FFFu + ((u >> 16) & 1u)) >> 16);
}
__device__ inline unsigned int pack2bf(float a, float b) {
    return (unsigned int)f2bf(a) | ((unsigned int)f2bf(b) << 16);
}
__device__ inline float2 bf2x(unsigned int u) {             // 2 bf16 -> 2 f32
    return make_float2(__uint_as_float(u << 16), __uint_as_float(u & 0xFFFF0000u));
}

// ---------------- CSR build ----------------
__global__ void k_count(const int* __restrict__ dst, int* __restrict__ counts) {
    int e = blockIdx.x * 256 + threadIdx.x;
    if (e < NE) atomicAdd(&counts[dst[e]], 1);
}

__global__ void k_scanA(const int* __restrict__ counts, int* __restrict__ indptr,
                        int* __restrict__ bsum) {
    __shared__ int sh[256];
    int t = threadIdx.x;
    int idx = blockIdx.x * 256 + t;
    int c = idx < NN ? counts[idx] : 0;
    sh[t] = c;
    __syncthreads();
    for (int off = 1; off < 256; off <<= 1) {
        int v = (t >= off) ? sh[t - off] : 0;
        __syncthreads();
        sh[t] += v;
        __syncthreads();
    }
    if (idx < NN) indptr[idx] = sh[t] - c;
    if (t == 255) bsum[blockIdx.x] = sh[255];
}

__global__ void k_scanB(int* __restrict__ bsum, int nb) {
    __shared__ int sh[256];
    int t = threadIdx.x;
    int c = t < nb ? bsum[t] : 0;
    sh[t] = c;
    __syncthreads();
    for (int off = 1; off < 256; off <<= 1) {
        int v = (t >= off) ? sh[t - off] : 0;
        __syncthreads();
        sh[t] += v;
        __syncthreads();
    }
    if (t < nb) bsum[t] = sh[t] - c;
}

__global__ void k_scanC(int* __restrict__ indptr, const int* __restrict__ bsum,
                        int* __restrict__ fill) {
    int idx = blockIdx.x * 256 + threadIdx.x;
    if (idx < NN) {
        indptr[idx] += bsum[idx >> 8];
        fill[idx] = 0;
    }
    if (idx == 0) indptr[NN] = NE;
}

__global__ void k_scatter(const int* __restrict__ src, const int* __restrict__ dst,
                          const int* __restrict__ indptr, int* __restrict__ fill,
                          int* __restrict__ srcs) {
    int e = blockIdx.x * 256 + threadIdx.x;
    if (e < NE) {
        int d = dst[e];
        int pos = atomicAdd(&fill[d], 1);
        srcs[indptr[d] + pos] = src[e];
    }
}

// ---------------- precompute: wel/wer + W1^T(bf16) + W2^T(bf16, 48 cols) ----------------
__global__ void k_prep(const float* __restrict__ W1, const float* __restrict__ al,
                       const float* __restrict__ ar, const float* __restrict__ W2,
                       float* __restrict__ wel, float* __restrict__ wer,
                       unsigned short* __restrict__ W1Tb,
                       unsigned short* __restrict__ W2Tb) {
    int gid = blockIdx.x * 256 + threadIdx.x;
    int nth = gridDim.x * 256;
    const int TOT = 512 + 32768 + 48 * 256;
    for (int i = gid; i < TOT; i += nth) {
        if (i < 512) {
            int k = i >> 2, h = i & 3;
            float a = 0.f, b = 0.f;
            for (int dd = 0; dd < 64; ++dd) {
                float w = W1[k * 256 + h * 64 + dd];
                a = fmaf(w, al[h * 64 + dd], a);
                b = fmaf(w, ar[h * 64 + dd], b);
            }
            wel[i] = a;            // i == k*4+h
            wer[i] = b;
        } else if (i < 512 + 32768) {
            int j = i - 512;
            int col = j >> 7, k = j & 127;
            W1Tb[j] = f2bf(W1[k * 256 + col]);      // W1T [256 cols][128 k] bf16
        } else {
            int j = i - 512 - 32768;
            int col = j >> 8, kk = j & 255;         // [48 cols][256 k]
            W2Tb[j] = (col < NCLS) ? f2bf(W2[kk * 40 + col]) : (unsigned short)0;
        }
    }
}

// el1/er1[N,4] = x @ wel / x @ wer ; also emit bf16 copy of x
__global__ void k_elr1x(const float* __restrict__ x, const float* __restrict__ wel,
                        const float* __restrict__ wer, float* __restrict__ el1,
                        float* __restrict__ er1, unsigned short* __restrict__ xb) {
    __shared__ float xs[64 * 129];
    __shared__ float wels[512], wers[512];
    int t = threadIdx.x;
    int n0 = blockIdx.x * 64;
    wels[t] = wel[t]; wels[256 + t] = wel[256 + t];
    wers[t] = wer[t]; wers[256 + t] = wer[256 + t];
    for (int i = 0; i < 8; ++i) {
        int f = i * 256 + t;
        int row = f >> 5;
        int col4 = (f & 31) * 4;
        float4 v = make_float4(0.f, 0.f, 0.f, 0.f);
        if (n0 + row < NN) v = ((const float4*)x)[(size_t)n0 * 32 + f];
        xs[row * 129 + col4 + 0] = v.x;
        xs[row * 129 + col4 + 1] = v.y;
        xs[row * 129 + col4 + 2] = v.z;
        xs[row * 129 + col4 + 3] = v.w;
    }
    __syncthreads();
    int node = t & 63;
    int h = t >> 6;
    float a = 0.f, b = 0.f;
    for (int k = 0; k < 128; ++k) {
        float xv = xs[node * 129 + k];
        a = fmaf(xv, wels[k * 4 + h], a);
        b = fmaf(xv, wers[k * 4 + h], b);
    }
    if (n0 + node < NN) {
        el1[(size_t)(n0 + node) * 4 + h] = a;
        er1[(size_t)(n0 + node) * 4 + h] = b;
    }
    for (int i = 0; i < 4; ++i) {
        int g = (i * 256 + t) * 8;
        int row = g >> 7, col = g & 127;
        if (n0 + row < NN) {
            ushort4 lo, hi;
            lo.x = f2bf(xs[row * 129 + col + 0]);
            lo.y = f2bf(xs[row * 129 + col + 1]);
            lo.z = f2bf(xs[row * 129 + col + 2]);
            lo.w = f2bf(xs[row * 129 + col + 3]);
            hi.x = f2bf(xs[row * 129 + col + 4]);
            hi.y = f2bf(xs[row * 129 + col + 5]);
            hi.z = f2bf(xs[row * 129 + col + 6]);
            hi.w = f2bf(xs[row * 129 + col + 7]);
            *(ushort4*)&xb[(size_t)(n0 + row) * 128 + col] = lo;
            *(ushort4*)&xb[(size_t)(n0 + row) * 128 + col + 4] = hi;
        }
    }
}

// ---------------- fused layer-1: aggregate (8-deep) -> LDS -> MFMA @W1 -> ELU ----------------
// block = 16 dsts, 4 waves; phase 1: wave wv aggregates dsts wv*4..wv*4+3;
// phase 2: wave wv = head wv, A = 16 nodes from LDS, B = W1T from global.
#define XG_STRIDE 260      // uints per node (256 + 4 pad)
__global__ void k_agg1m(const unsigned int* __restrict__ xb32,
                        const float* __restrict__ el1, const float* __restrict__ er1,
                        const int* __restrict__ indptr, const int* __restrict__ srcs,
                        const unsigned short* __restrict__ W1Tb,
                        const float* __restrict__ b1,
                        unsigned short* __restrict__ elu1) {
    __shared__ unsigned int xg[16 * XG_STRIDE];    // 16.6 KB
    __shared__ int   si[4][64];
    __shared__ float4 sw[4][64];
    int t = threadIdx.x;
    int wv = t >> 6, l = t & 63;
    int n0 = blockIdx.x * 16;
    for (int rr = 0; rr < 4; ++rr) {
        int node = wv * 4 + rr;
        int d = n0 + node;
        int beg = indptr[d], end = indptr[d + 1];
        int deg = end - beg;
        float4 rd = *(const float4*)&er1[(size_t)d * 4];
        // ---- softmax weights (lane-parallel over edges) ----
        int s_l = 0;
        float4 w = make_float4(0.f, 0.f, 0.f, 0.f);
        if (l < deg) {
            s_l = srcs[beg + l];
            float4 ls = *(const float4*)&el1[(size_t)s_l * 4];
            float e0 = ls.x + rd.x, e1 = ls.y + rd.y, e2 = ls.z + rd.z, e3 = ls.w + rd.w;
            e0 = e0 > 0.f ? e0 : 0.2f * e0;
            e1 = e1 > 0.f ? e1 : 0.2f * e1;
            e2 = e2 > 0.f ? e2 : 0.2f * e2;
            e3 = e3 > 0.f ? e3 : 0.2f * e3;
            w = make_float4(__expf(e0), __expf(e1), __expf(e2), __expf(e3));
        }
        float s0 = w.x, s1 = w.y, s2 = w.z, s3 = w.w;
        for (int j = beg + 64 + l; j < end; j += 64) {     // deg>64 (rare)
            float4 ls = *(const float4*)&el1[(size_t)srcs[j] * 4];
            float e0 = ls.x + rd.x, e1 = ls.y + rd.y, e2 = ls.z + rd.z, e3 = ls.w + rd.w;
            e0 = e0 > 0.f ? e0 : 0.2f * e0;
            e1 = e1 > 0.f ? e1 : 0.2f * e1;
            e2 = e2 > 0.f ? e2 : 0.2f * e2;
            e3 = e3 > 0.f ? e3 : 0.2f * e3;
            s0 += __expf(e0); s1 += __expf(e1); s2 += __expf(e2); s3 += __expf(e3);
        }
#pragma unroll
        for (int off = 32; off > 0; off >>= 1) {
            s0 += __shfl_xor(s0, off);
            s1 += __shfl_xor(s1, off);
            s2 += __shfl_xor(s2, off);
            s3 += __shfl_xor(s3, off);
        }
        float i0 = s0 > 0.f ? 1.f / s0 : 0.f;
        float i1 = s1 > 0.f ? 1.f / s1 : 0.f;
        float i2 = s2 > 0.f ? 1.f / s2 : 0.f;
        float i3 = s3 > 0.f ? 1.f / s3 : 0.f;
        si[wv][l] = s_l;
        sw[wv][l] = make_float4(w.x * i0, w.y * i1, w.z * i2, w.w * i3);
        // ---- gather: 8 independent rows in flight ----
        float2 a0 = {0.f, 0.f}, a1 = {0.f, 0.f}, a2 = {0.f, 0.f}, a3 = {0.f, 0.f};
        int dege = deg < 64 ? deg : 64;
        for (int e = 0; e < dege; e += 8) {
            int ixs[8];
            float4 wss[8];
            unsigned int us[8];
#pragma unroll
            for (int q = 0; q < 8; ++q) {
                ixs[q] = si[wv][e + q];
                wss[q] = sw[wv][e + q];
            }
#pragma unroll
            for (int q = 0; q < 8; ++q) us[q] = xb32[(size_t)ixs[q] * 64 + l];
#pragma unroll
            for (int q = 0; q < 8; ++q) {
                float2 xv = bf2x(us[q]);
                float4 wq = wss[q];
                a0.x = fmaf(wq.x, xv.x, a0.x); a0.y = fmaf(wq.x, xv.y, a0.y);
                a1.x = fmaf(wq.y, xv.x, a1.x); a1.y = fmaf(wq.y, xv.y, a1.y);
                a2.x = fmaf(wq.z, xv.x, a2.x); a2.y = fmaf(wq.z, xv.y, a2.y);
                a3.x = fmaf(wq.w, xv.x, a3.x); a3.y = fmaf(wq.w, xv.y, a3.y);
            }
        }
        for (int j = beg + 64; j < end; ++j) {             // deg>64 (rare)
            int s = srcs[j];
            float4 ls = *(const float4*)&el1[(size_t)s * 4];
            float e0 = ls.x + rd.x, e1 = ls.y + rd.y, e2 = ls.z + rd.z, e3 = ls.w + rd.w;
            e0 = e0 > 0.f ? e0 : 0.2f * e0;
            e1 = e1 > 0.f ? e1 : 0.2f * e1;
            e2 = e2 > 0.f ? e2 : 0.2f * e2;
            e3 = e3 > 0.f ? e3 : 0.2f * e3;
            float w0 = __expf(e0) * i0, w1 = __expf(e1) * i1;
            float w2 = __expf(e2) * i2, w3 = __expf(e3) * i3;
            float2 xv = bf2x(xb32[(size_t)s * 64 + l]);
            a0.x = fmaf(w0, xv.x, a0.x); a0.y = fmaf(w0, xv.y, a0.y);
            a1.x = fmaf(w1, xv.x, a1.x); a1.y = fmaf(w1, xv.y, a1.y);
            a2.x = fmaf(w2, xv.x, a2.x); a2.y = fmaf(w2, xv.y, a2.y);
            a3.x = fmaf(w3, xv.x, a3.x); a3.y = fmaf(w3, xv.y, a3.y);
        }
        unsigned int* xgn = &xg[node * XG_STRIDE];
        xgn[0 * 64 + l] = pack2bf(a0.x, a0.y);
        xgn[1 * 64 + l] = pack2bf(a1.x, a1.y);
        xgn[2 * 64 + l] = pack2bf(a2.x, a2.y);
        xgn[3 * 64 + l] = pack2bf(a3.x, a3.y);
    }
    __syncthreads();
    // ---- MFMA phase: wave wv = head wv; 16 nodes x 64 cols, K=128 ----
    int lrow = l & 15, lk = l >> 4;
    f32x4 acc[4] = {};
#pragma unroll
    for (int kt = 0; kt < 4; ++kt) {
        int kofs_u = kt * 16 + lk * 4;                 // uints
        bf16x8 av = *(const bf16x8*)&xg[lrow * XG_STRIDE + wv * 64 + kofs_u];
#pragma unroll
        for (int nt = 0; nt < 4; ++nt) {
            int col = wv * 64 + nt * 16 + lrow;
            bf16x8 bv = *(const bf16x8*)&W1Tb[(size_t)col * 128 + kt * 32 + lk * 8];
            acc[nt] = __builtin_amdgcn_mfma_f32_16x16x32_bf16(av, bv, acc[nt], 0, 0, 0);
        }
    }
#pragma unroll
    for (int nt = 0; nt < 4; ++nt) {
        int col = wv * 64 + nt * 16 + lrow;
        float bv = b1[col];
#pragma unroll
        for (int r = 0; r < 4; ++r) {
            int row = n0 + lk * 4 + r;
            float o = acc[nt][r] + bv;
            o = o > 0.f ? o : (__expf(o) - 1.f);
            elu1[(size_t)row * 256 + col] = f2bf(o);
        }
    }
}

// ---------------- layer 2: MFMA GEMM [N,256]@[256,48] + fused el2/er2 ----------------
__global__ void k_mfma2(const unsigned short* __restrict__ elu1,
                        const unsigned short* __restrict__ W2Tb,
                        const float* __restrict__ al2, const float* __restrict__ ar2,
                        unsigned short* __restrict__ h2b, float* __restrict__ el2,
                        float* __restrict__ er2) {
    int t = threadIdx.x;
    int wv = t >> 6, l = t & 63;
    int lrow = l & 15, lk = l >> 4;
    int n0 = blockIdx.x * 64 + wv * 16;
    int arow = n0 + lrow;
    if (arow >= NN) arow = NN - 1;
    f32x4 acc[3] = {};
#pragma unroll
    for (int kt = 0; kt < 8; ++kt) {
        int kofs = kt * 32 + lk * 8;
        bf16x8 av = *(const bf16x8*)&elu1[(size_t)arow * 256 + kofs];
#pragma unroll
        for (int nt = 0; nt < 3; ++nt) {
            bf16x8 bv = *(const bf16x8*)&W2Tb[(size_t)(nt * 16 + lrow) * 256 + kofs];
            acc[nt] = __builtin_amdgcn_mfma_f32_16x16x32_bf16(av, bv, acc[nt], 0, 0, 0);
        }
    }
    float alc[3], arc[3];
#pragma unroll
    for (int nt = 0; nt < 3; ++nt) {
        int col = nt * 16 + lrow;
        alc[nt] = col < NCLS ? al2[col] : 0.f;
        arc[nt] = col < NCLS ? ar2[col] : 0.f;
    }
#pragma unroll
    for (int r = 0; r < 4; ++r) {
        int row = n0 + lk * 4 + r;
        float pa = 0.f, pb = 0.f;
#pragma unroll
        for (int nt = 0; nt < 3; ++nt) {
            float v = acc[nt][r];
            pa = fmaf(v, alc[nt], pa);
            pb = fmaf(v, arc[nt], pb);
            int col = nt * 16 + lrow;
            if (row < NN && col < NCLS) h2b[(size_t)row * NCLS + col] = f2bf(v);
        }
#pragma unroll
        for (int off = 1; off < 16; off <<= 1) {
            pa += __shfl_xor(pa, off);
            pb += __shfl_xor(pb, off);
        }
        if (lrow == 0 && row < NN) {
            el2[row] = pa;
            er2[row] = pb;
        }
    }
}

// merged layer-2 softmax + aggregation: wave per dst, half-wave edge split, uint payload
__global__ void k_agg2(const unsigned int* __restrict__ h2b32,
                       const float* __restrict__ el2,
                       const float* __restrict__ er2, const float* __restrict__ b2,
                       const int* __restrict__ indptr, const int* __restrict__ srcs,
                       float* __restrict__ out) {
    __shared__ int   si[4][64];
    __shared__ float sw[4][64];
    int t = threadIdx.x;
    int wv = t >> 6, l = t & 63;
    int d = blockIdx.x * 4 + wv;
    int beg = indptr[d], end = indptr[d + 1];
    int deg = end - beg;
    float rd = er2[d];
    int s_l = 0;
    float w = 0.f;
    if (l < deg) {
        s_l = srcs[beg + l];
        float e = el2[s_l] + rd;
        e = e > 0.f ? e : 0.2f * e;
        w = __expf(e);
    }
    float sum = w;
    for (int j = beg + 64 + l; j < end; j += 64) {
        float e = el2[srcs[j]] + rd;
        e = e > 0.f ? e : 0.2f * e;
        sum += __expf(e);
    }
#pragma unroll
    for (int off = 32; off > 0; off >>= 1) sum += __shfl_xor(sum, off);
    float inv = sum > 0.f ? 1.f / sum : 0.f;
    si[wv][l] = s_l;
    sw[wv][l] = w * inv;
    // payload: half-wave edge split; lane il holds cols {2*il, 2*il+1}
    int half = l >> 5, il = l & 31;
    bool act = il < 20;
    float2 acc = {0.f, 0.f};
    int dege = deg < 64 ? deg : 64;
    for (int e = 0; e < dege; e += 8) {
        int ixs[4];
        float ws_[4];
        unsigned int us[4];
#pragma unroll
        for (int q = 0; q < 4; ++q) {
            int idx = e + 2 * q + half;
            ixs[q] = si[wv][idx];
            ws_[q] = sw[wv][idx];
        }
#pragma unroll
        for (int q = 0; q < 4; ++q)
            us[q] = act ? h2b32[(size_t)ixs[q] * 20 + il] : 0u;
#pragma unroll
        for (int q = 0; q < 4; ++q) {
            float2 xv = bf2x(us[q]);
            acc.x = fmaf(ws_[q], xv.x, acc.x);
            acc.y = fmaf(ws_[q], xv.y, acc.y);
        }
    }
    for (int j = beg + 64; j < end; ++j) {     // deg>64 (rare)
        int s = srcs[j];
        float e = el2[s] + rd;
        e = e > 0.f ? e : 0.2f * e;
        float ww = (half == 0) ? __expf(e) * inv : 0.f;
        unsigned int u = act ? h2b32[(size_t)s * 20 + il] : 0u;
        float2 xv = bf2x(u);
        acc.x = fmaf(ww, xv.x, acc.x);
        acc.y = fmaf(ww, xv.y, acc.y);
    }
    acc.x += __shfl_xor(acc.x, 32);
    acc.y += __shfl_xor(acc.y, 32);
    if (half == 0 && act) {
        float2 bb = *(const float2*)&b2[2 * il];
        *(float2*)&out[(size_t)d * NCLS + 2 * il] =
            make_float2(acc.x + bb.x, acc.y + bb.y);
    }
}

extern "C" void kernel_launch(void* const* d_in, const int* in_sizes, int n_in,
                              void* d_out, int out_size, void* d_ws, size_t ws_size,
                              hipStream_t stream) {
    const float* x   = (const float*)d_in[0];
    const int*   src = (const int*)d_in[1];
    const int*   dst = (const int*)d_in[2];
    const float* W1  = (const float*)d_in[3];
    const float* al1 = (const float*)d_in[4];
    const float* ar1 = (const float*)d_in[5];
    const float* b1  = (const float*)d_in[6];
    const float* W2  = (const float*)d_in[7];
    const float* al2 = (const float*)d_in[8];
    const float* ar2 = (const float*)d_in[9];
    const float* b2  = (const float*)d_in[10];
    float* out = (float*)d_out;

    float* ws = (float*)d_ws;
    size_t off = 0;
    unsigned short* elu1  = (unsigned short*)(ws + off); off += (size_t)NN * 128; // bf16 [N,256]
    unsigned short* xb    = (unsigned short*)(ws + off); off += (size_t)NN * 64;  // bf16 [N,128]
    unsigned short* h2b   = (unsigned short*)(ws + off); off += (size_t)NN * 20;  // bf16 [N,40]
    float* el1  = ws + off; off += (size_t)NN * 4;
    float* er1  = ws + off; off += (size_t)NN * 4;
    float* el2  = ws + off; off += NN;
    float* er2  = ws + off; off += NN;
    float* wel  = ws + off; off += 512;
    float* wer  = ws + off; off += 512;
    unsigned short* w1tb = (unsigned short*)(ws + off); off += 16384;             // bf16 [256,128]
    unsigned short* w2tb = (unsigned short*)(ws + off); off += 48 * 128;          // bf16 [48,256]
    int* counts = (int*)(ws + off);
    int* indptr = counts + NN;
    int* fill   = indptr + NN + 1;
    int* srcs   = fill + NN;
    int* bsum   = srcs + NE;

    const int NB = (NN + 255) / 256;

    hipMemsetAsync(counts, 0, NN * sizeof(int), stream);

    k_count<<<(NE + 255) / 256, 256, 0, stream>>>(dst, counts);
    k_scanA<<<NB, 256, 0, stream>>>(counts, indptr, bsum);
    k_scanB<<<1, 256, 0, stream>>>(bsum, NB);
    k_scanC<<<NB, 256, 0, stream>>>(indptr, bsum, fill);
    k_scatter<<<(NE + 255) / 256, 256, 0, stream>>>(src, dst, indptr, fill, srcs);

    k_prep<<<48, 256, 0, stream>>>(W1, al1, ar1, W2, wel, wer, w1tb, w2tb);
    k_elr1x<<<(NN + 63) / 64, 256, 0, stream>>>(x, wel, wer, el1, er1, xb);
    k_agg1m<<<NN / 16, 256, 0, stream>>>((const unsigned int*)xb, el1, er1, indptr, srcs,
                                         w1tb, b1, elu1);

    k_mfma2<<<(NN + 63) / 64, 256, 0, stream>>>(elu1, w2tb, al2, ar2, h2b, el2, er2);
    k_agg2<<<NN / 4, 256, 0, stream>>>((const unsigned int*)h2b, el2, er2, b2,
                                       indptr, srcs, out);
}